// Round 11
// baseline (742.867 us; speedup 1.0000x reference)
//
#include <hip/hip_runtime.h>

#define DD 128      // feature dim
#define PAD_I 64    // max item in-degree (Poisson(16); P(overflow) ~ 1e-6, guarded)
#define PAD_U 48    // max user in-degree (Poisson(8);  P(overflow) ~ 1e-9, guarded)

typedef __attribute__((ext_vector_type(8))) short bf16x8;
typedef __attribute__((ext_vector_type(4))) float f32x4;

// RNE fp32 -> bf16 split: x ~= hi + lo with |x - hi - lo| <= 2^-18 |x|
__device__ __forceinline__ void split2(float x, unsigned short& h, unsigned short& l) {
    unsigned int u = __float_as_uint(x);
    unsigned int hb = (u + 0x7FFFu + ((u >> 16) & 1u)) >> 16;
    h = (unsigned short)hb;
    float r = x - __uint_as_float(hb << 16);
    unsigned int v = __float_as_uint(r);
    l = (unsigned short)((v + 0x7FFFu + ((v >> 16) & 1u)) >> 16);
}

// load 8 contiguous fp32 (optionally relu) and split into hi/lo bf16 frags
template <bool R>
__device__ __forceinline__ void load_split8(const float* __restrict__ p,
                                            bf16x8& hf, bf16x8& lf) {
    float4 v0 = *reinterpret_cast<const float4*>(p);
    float4 v1 = *reinterpret_cast<const float4*>(p + 4);
    float x[8] = {v0.x, v0.y, v0.z, v0.w, v1.x, v1.y, v1.z, v1.w};
#pragma unroll
    for (int j = 0; j < 8; ++j) {
        float xv = R ? fmaxf(x[j], 0.f) : x[j];
        unsigned short h, l;
        split2(xv, h, l);
        hf[j] = (short)h;
        lf[j] = (short)l;
    }
}

// r10-verified gather: per wave, 16 rows (local rows w*16..w*16+15) mean-gathered
// into lds[localrow][0..127]; 32 lanes x float4 per edge, DIRECT pl[j] index loads,
// 2 edges in flight (pairs (j, j+2) stride 4 + guarded tail), xor-32 reduce.
template <bool RELU>
__device__ __forceinline__ void gather_to_lds(const float* __restrict__ feat,
                                              const int* __restrict__ deg,
                                              const int* __restrict__ adj, int PAD,
                                              float (*agg)[DD + 4],
                                              int base, int w, int l, int N) {
    const int p = l >> 5, c = l & 31;
    for (int rr = 0; rr < 16; ++rr) {
        const int row = base + w * 16 + rr;
        if (row >= N) continue;                 // wave-uniform branch
        int dg = deg[row]; if (dg > PAD) dg = PAD;
        const int* pl = adj + (size_t)row * PAD;

        float4 a0 = make_float4(0.f, 0.f, 0.f, 0.f);
        float4 a1 = make_float4(0.f, 0.f, 0.f, 0.f);
        int j = p;
        for (; j + 2 < dg; j += 4) {
            int s0 = pl[j];
            int s1 = pl[j + 2];
            float4 v0 = *reinterpret_cast<const float4*>(feat + (size_t)s0 * DD + c * 4);
            float4 v1 = *reinterpret_cast<const float4*>(feat + (size_t)s1 * DD + c * 4);
            if (RELU) {
                v0.x = fmaxf(v0.x, 0.f); v0.y = fmaxf(v0.y, 0.f);
                v0.z = fmaxf(v0.z, 0.f); v0.w = fmaxf(v0.w, 0.f);
                v1.x = fmaxf(v1.x, 0.f); v1.y = fmaxf(v1.y, 0.f);
                v1.z = fmaxf(v1.z, 0.f); v1.w = fmaxf(v1.w, 0.f);
            }
            a0.x += v0.x; a0.y += v0.y; a0.z += v0.z; a0.w += v0.w;
            a1.x += v1.x; a1.y += v1.y; a1.z += v1.z; a1.w += v1.w;
        }
        if (j < dg) {
            int s = pl[j];
            float4 v = *reinterpret_cast<const float4*>(feat + (size_t)s * DD + c * 4);
            if (RELU) {
                v.x = fmaxf(v.x, 0.f); v.y = fmaxf(v.y, 0.f);
                v.z = fmaxf(v.z, 0.f); v.w = fmaxf(v.w, 0.f);
            }
            a0.x += v.x; a0.y += v.y; a0.z += v.z; a0.w += v.w;
        }
        a0.x += a1.x; a0.y += a1.y; a0.z += a1.z; a0.w += a1.w;

        a0.x += __shfl_xor(a0.x, 32);
        a0.y += __shfl_xor(a0.y, 32);
        a0.z += __shfl_xor(a0.z, 32);
        a0.w += __shfl_xor(a0.w, 32);
        if (p == 0) {
            float iv = 1.0f / (float)(dg > 1 ? dg : 1);
            a0.x *= iv; a0.y *= iv; a0.z *= iv; a0.w *= iv;
            *reinterpret_cast<float4*>(&agg[w * 16 + rr][c * 4]) = a0;
        }
    }
}

// ---------------- misc kernels ----------------

__global__ __launch_bounds__(256) void zeroi_k(int* __restrict__ p, int n) {
    int gid = blockIdx.x * 256 + threadIdx.x;
    if (gid < n) p[gid] = 0;
}

__global__ __launch_bounds__(256) void fill_k(const int* __restrict__ src,
                                              const int* __restrict__ dst,
                                              int* __restrict__ cur,
                                              int* __restrict__ pad, int PAD, int E) {
    int e = blockIdx.x * 256 + threadIdx.x;
    if (e >= E) return;
    int d = dst[e];
    int slot = atomicAdd(&cur[d], 1);
    if (slot < PAD) pad[(size_t)d * PAD + slot] = src[e];
}

// out[n] = dot(x[n][:], hw) + hb
__global__ __launch_bounds__(256) void head_k(const float* __restrict__ x,
                                              const float* __restrict__ hw,
                                              const float* __restrict__ hb,
                                              float* __restrict__ out, int N) {
    int wid = threadIdx.x >> 6, lane = threadIdx.x & 63;
    int row = blockIdx.x * 4 + wid;
    if (row >= N) return;
    const float* xr = x + (size_t)row * DD;
    float v = xr[lane] * hw[lane] + xr[lane + 64] * hw[lane + 64];
    for (int off = 32; off > 0; off >>= 1) v += __shfl_down(v, off);
    if (lane == 0) out[row] = v + hb[0];
}

// ---------------- weight pre-split into PACKED fragment-order bf16 planes ----------------
// Packed p = ((kc*8 + t)*64 + lane)*8 + j  <->  W[t*16 + (lane&15)][kc*32 + (lane>>4)*8 + j]

struct W12 { const float* p[12]; };

__global__ __launch_bounds__(256) void wsplit_k(W12 ws, unsigned short* __restrict__ hi,
                                                unsigned short* __restrict__ lo) {
    int idx = blockIdx.x * 256 + threadIdx.x;
    if (idx >= 12 * DD * DD) return;
    int m = idx >> 14, pk = idx & 16383;
    int j = pk & 7, lane = (pk >> 3) & 63, t = (pk >> 9) & 7, kc = (pk >> 12) & 3;
    int src = (t * 16 + (lane & 15)) * DD + kc * 32 + (lane >> 4) * 8 + j;
    unsigned short h, l;
    split2(ws.p[m][src], h, l);
    hi[idx] = h;
    lo[idx] = l;
}

// ---------------- split-bf16 MFMA GEMM kernels ----------------
// FULL 3-product split: ah*bh + al*bh + ah*bl (~2^-18 residual).
// mfma_f32_16x16x32_bf16: A/B row = lane&15, k = (lane>>4)*8 + j; C/D col = lane&15,
// row = (lane>>4)*4 + reg.  4 waves, 16 rows/wave, 64-row blocks.

// fused gather + steps 2+3:
//   h = relu(X@W1^T+b1) -> LDS; A2-frags <- LDS; LDS reused: agg = gather-mean(feat,adj);
//   pred = h@W2^T; out = agg - (pred+b2)*(deg>0)   (pure store into Io)
template <bool RELX, bool RELF>
__global__ __launch_bounds__(256) void fused23g_k(
        const float* __restrict__ X,
        const unsigned short* __restrict__ W1h, const unsigned short* __restrict__ W1l,
        const float* __restrict__ B1,
        const unsigned short* __restrict__ W2h, const unsigned short* __restrict__ W2l,
        const float* __restrict__ B2,
        const float* __restrict__ feat, const int* __restrict__ adj, int PAD,
        const int* __restrict__ deg,
        float* __restrict__ Io, int N) {
    __shared__ __align__(16) float hl[64][DD + 4];   // h, then reused as agg

    const int tid = threadIdx.x;
    const int w = tid >> 6, l = tid & 63;
    const int l15 = l & 15, lq = l >> 4;
    const int base = blockIdx.x * 64;

    const int rowA = base + w * 16 + l15;
    const int rA = rowA < N ? rowA : N - 1;
    const float* xp = X + (size_t)rA * DD;

    bf16x8 ah[4], al[4];
#pragma unroll
    for (int kc = 0; kc < 4; ++kc)
        load_split8<RELX>(xp + kc * 32 + lq * 8, ah[kc], al[kc]);

    f32x4 acc[8];
#pragma unroll
    for (int t = 0; t < 8; ++t) acc[t] = (f32x4){0.f, 0.f, 0.f, 0.f};

#pragma unroll
    for (int kc = 0; kc < 4; ++kc) {
        const size_t fb = ((size_t)(kc * 8) * 64 + l) * 8;
        bf16x8 bh[8], bl[8];
#pragma unroll
        for (int t = 0; t < 8; ++t) bh[t] = *reinterpret_cast<const bf16x8*>(W1h + fb + t * 512);
#pragma unroll
        for (int t = 0; t < 8; ++t) bl[t] = *reinterpret_cast<const bf16x8*>(W1l + fb + t * 512);
#pragma unroll
        for (int t = 0; t < 8; ++t)
            acc[t] = __builtin_amdgcn_mfma_f32_16x16x32_bf16(ah[kc], bh[t], acc[t], 0, 0, 0);
#pragma unroll
        for (int t = 0; t < 8; ++t)
            acc[t] = __builtin_amdgcn_mfma_f32_16x16x32_bf16(al[kc], bh[t], acc[t], 0, 0, 0);
#pragma unroll
        for (int t = 0; t < 8; ++t)
            acc[t] = __builtin_amdgcn_mfma_f32_16x16x32_bf16(ah[kc], bl[t], acc[t], 0, 0, 0);
    }

    // h = relu(acc + b1) -> LDS fp32 (C/D layout rows w*16+lq*4+r)
    const int lr0 = w * 16 + lq * 4;
#pragma unroll
    for (int t = 0; t < 8; ++t) {
        const int col = t * 16 + l15;
        const float b = B1[col];
#pragma unroll
        for (int r = 0; r < 4; ++r)
            hl[lr0 + r][col] = fmaxf(acc[t][r] + b, 0.f);
    }
    __syncthreads();

    // read h back in A-frag layout + split (full fidelity)
    bf16x8 ah2[4], al2[4];
#pragma unroll
    for (int kc = 0; kc < 4; ++kc)
        load_split8<false>(&hl[w * 16 + l15][kc * 32 + lq * 8], ah2[kc], al2[kc]);
    __syncthreads();   // all h reads done before LDS is reused for agg

    // gather-mean into the same LDS buffer
    gather_to_lds<RELF>(feat, deg, adj, PAD, hl, base, w, l, N);
    __syncthreads();

#pragma unroll
    for (int t = 0; t < 8; ++t) acc[t] = (f32x4){0.f, 0.f, 0.f, 0.f};

#pragma unroll
    for (int kc = 0; kc < 4; ++kc) {
        const size_t fb = ((size_t)(kc * 8) * 64 + l) * 8;
        bf16x8 bh[8], bl[8];
#pragma unroll
        for (int t = 0; t < 8; ++t) bh[t] = *reinterpret_cast<const bf16x8*>(W2h + fb + t * 512);
#pragma unroll
        for (int t = 0; t < 8; ++t) bl[t] = *reinterpret_cast<const bf16x8*>(W2l + fb + t * 512);
#pragma unroll
        for (int t = 0; t < 8; ++t)
            acc[t] = __builtin_amdgcn_mfma_f32_16x16x32_bf16(ah2[kc], bh[t], acc[t], 0, 0, 0);
#pragma unroll
        for (int t = 0; t < 8; ++t)
            acc[t] = __builtin_amdgcn_mfma_f32_16x16x32_bf16(al2[kc], bh[t], acc[t], 0, 0, 0);
#pragma unroll
        for (int t = 0; t < 8; ++t)
            acc[t] = __builtin_amdgcn_mfma_f32_16x16x32_bf16(ah2[kc], bl[t], acc[t], 0, 0, 0);
    }

    // epilogue: Io = agg - (acc + b2) * (deg>0)   (agg read from LDS; pure global store)
#pragma unroll
    for (int t = 0; t < 8; ++t) {
        const int col = t * 16 + l15;
        const float b2v = B2[col];
#pragma unroll
        for (int r = 0; r < 4; ++r) {
            const int grow = base + w * 16 + lq * 4 + r;
            if (grow >= N) continue;
            float fl = deg[grow] > 0 ? 1.f : 0.f;
            float am = hl[w * 16 + lq * 4 + r][col];
            Io[(size_t)grow * DD + col] = am - (acc[t][r] + b2v) * fl;
        }
    }
}

// dual GEMM (64-row blocks, r6-verified): out = relu( X1@W1^T + b1 + X2@W2^T + b2 );
// out may alias X1 (each wave reads only the rows it writes; reads precede stores).
template <bool RELX2>
__global__ __launch_bounds__(256) void gemm_dual_k(
        const float* __restrict__ X1,
        const unsigned short* __restrict__ W1h, const unsigned short* __restrict__ W1l,
        const float* __restrict__ B1,
        const float* __restrict__ X2,
        const unsigned short* __restrict__ W2h, const unsigned short* __restrict__ W2l,
        const float* __restrict__ B2,
        float* __restrict__ out, int N) {
    const int tid = threadIdx.x;
    const int w = tid >> 6, l = tid & 63;
    const int l15 = l & 15, lq = l >> 4;

    const int rowA = blockIdx.x * 64 + w * 16 + l15;
    const int rA = rowA < N ? rowA : N - 1;

    f32x4 acc[8];
#pragma unroll
    for (int t = 0; t < 8; ++t) acc[t] = (f32x4){0.f, 0.f, 0.f, 0.f};

    {
        bf16x8 ah[4], al[4];
#pragma unroll
        for (int kc = 0; kc < 4; ++kc)
            load_split8<false>(X1 + (size_t)rA * DD + kc * 32 + lq * 8, ah[kc], al[kc]);
#pragma unroll
        for (int kc = 0; kc < 4; ++kc) {
            const size_t fb = ((size_t)(kc * 8) * 64 + l) * 8;
            bf16x8 bh[8], bl[8];
#pragma unroll
            for (int t = 0; t < 8; ++t) bh[t] = *reinterpret_cast<const bf16x8*>(W1h + fb + t * 512);
#pragma unroll
            for (int t = 0; t < 8; ++t) bl[t] = *reinterpret_cast<const bf16x8*>(W1l + fb + t * 512);
#pragma unroll
            for (int t = 0; t < 8; ++t)
                acc[t] = __builtin_amdgcn_mfma_f32_16x16x32_bf16(ah[kc], bh[t], acc[t], 0, 0, 0);
#pragma unroll
            for (int t = 0; t < 8; ++t)
                acc[t] = __builtin_amdgcn_mfma_f32_16x16x32_bf16(al[kc], bh[t], acc[t], 0, 0, 0);
#pragma unroll
            for (int t = 0; t < 8; ++t)
                acc[t] = __builtin_amdgcn_mfma_f32_16x16x32_bf16(ah[kc], bl[t], acc[t], 0, 0, 0);
        }
    }
    {
        bf16x8 ah[4], al[4];
#pragma unroll
        for (int kc = 0; kc < 4; ++kc)
            load_split8<RELX2>(X2 + (size_t)rA * DD + kc * 32 + lq * 8, ah[kc], al[kc]);
#pragma unroll
        for (int kc = 0; kc < 4; ++kc) {
            const size_t fb = ((size_t)(kc * 8) * 64 + l) * 8;
            bf16x8 bh[8], bl[8];
#pragma unroll
            for (int t = 0; t < 8; ++t) bh[t] = *reinterpret_cast<const bf16x8*>(W2h + fb + t * 512);
#pragma unroll
            for (int t = 0; t < 8; ++t) bl[t] = *reinterpret_cast<const bf16x8*>(W2l + fb + t * 512);
#pragma unroll
            for (int t = 0; t < 8; ++t)
                acc[t] = __builtin_amdgcn_mfma_f32_16x16x32_bf16(ah[kc], bh[t], acc[t], 0, 0, 0);
#pragma unroll
            for (int t = 0; t < 8; ++t)
                acc[t] = __builtin_amdgcn_mfma_f32_16x16x32_bf16(al[kc], bh[t], acc[t], 0, 0, 0);
#pragma unroll
            for (int t = 0; t < 8; ++t)
                acc[t] = __builtin_amdgcn_mfma_f32_16x16x32_bf16(ah[kc], bl[t], acc[t], 0, 0, 0);
        }
    }

    const int orow0 = blockIdx.x * 64 + w * 16 + lq * 4;
#pragma unroll
    for (int t = 0; t < 8; ++t) {
        const int col = t * 16 + l15;
        const float bias = B1[col] + B2[col];
#pragma unroll
        for (int r = 0; r < 4; ++r) {
            const int grow = orow0 + r;
            if (grow >= N) continue;
            out[(size_t)grow * DD + col] = fmaxf(acc[t][r] + bias, 0.f);
        }
    }
}

// fused gather + dual GEMM: agg = gather-mean(feat,adj) -> LDS;
// out = relu( agg@W1^T + b1 + X2@W2^T + b2 )
template <bool RELF, bool RELX2>
__global__ __launch_bounds__(256) void dualg_k(
        const float* __restrict__ feat, const int* __restrict__ adj, int PAD,
        const int* __restrict__ deg,
        const unsigned short* __restrict__ W1h, const unsigned short* __restrict__ W1l,
        const float* __restrict__ B1,
        const float* __restrict__ X2,
        const unsigned short* __restrict__ W2h, const unsigned short* __restrict__ W2l,
        const float* __restrict__ B2,
        float* __restrict__ out, int N) {
    __shared__ __align__(16) float ag[64][DD + 4];

    const int tid = threadIdx.x;
    const int w = tid >> 6, l = tid & 63;
    const int l15 = l & 15, lq = l >> 4;
    const int base = blockIdx.x * 64;

    const int rowA = base + w * 16 + l15;
    const int rA = rowA < N ? rowA : N - 1;

    // X2 loads issued first (independent of gather)
    bf16x8 a2h[4], a2l[4];
#pragma unroll
    for (int kc = 0; kc < 4; ++kc)
        load_split8<RELX2>(X2 + (size_t)rA * DD + kc * 32 + lq * 8, a2h[kc], a2l[kc]);

    // gather-mean into LDS
    gather_to_lds<RELF>(feat, deg, adj, PAD, ag, base, w, l, N);
    __syncthreads();

    // A1 frags from LDS + split
    bf16x8 ah[4], al[4];
#pragma unroll
    for (int kc = 0; kc < 4; ++kc)
        load_split8<false>(&ag[w * 16 + l15][kc * 32 + lq * 8], ah[kc], al[kc]);

    f32x4 acc[8];
#pragma unroll
    for (int t = 0; t < 8; ++t) acc[t] = (f32x4){0.f, 0.f, 0.f, 0.f};

#pragma unroll
    for (int kc = 0; kc < 4; ++kc) {
        const size_t fb = ((size_t)(kc * 8) * 64 + l) * 8;
        bf16x8 bh[8], bl[8];
#pragma unroll
        for (int t = 0; t < 8; ++t) bh[t] = *reinterpret_cast<const bf16x8*>(W1h + fb + t * 512);
#pragma unroll
        for (int t = 0; t < 8; ++t) bl[t] = *reinterpret_cast<const bf16x8*>(W1l + fb + t * 512);
#pragma unroll
        for (int t = 0; t < 8; ++t)
            acc[t] = __builtin_amdgcn_mfma_f32_16x16x32_bf16(ah[kc], bh[t], acc[t], 0, 0, 0);
#pragma unroll
        for (int t = 0; t < 8; ++t)
            acc[t] = __builtin_amdgcn_mfma_f32_16x16x32_bf16(al[kc], bh[t], acc[t], 0, 0, 0);
#pragma unroll
        for (int t = 0; t < 8; ++t)
            acc[t] = __builtin_amdgcn_mfma_f32_16x16x32_bf16(ah[kc], bl[t], acc[t], 0, 0, 0);
    }
#pragma unroll
    for (int kc = 0; kc < 4; ++kc) {
        const size_t fb = ((size_t)(kc * 8) * 64 + l) * 8;
        bf16x8 bh[8], bl[8];
#pragma unroll
        for (int t = 0; t < 8; ++t) bh[t] = *reinterpret_cast<const bf16x8*>(W2h + fb + t * 512);
#pragma unroll
        for (int t = 0; t < 8; ++t) bl[t] = *reinterpret_cast<const bf16x8*>(W2l + fb + t * 512);
#pragma unroll
        for (int t = 0; t < 8; ++t)
            acc[t] = __builtin_amdgcn_mfma_f32_16x16x32_bf16(a2h[kc], bh[t], acc[t], 0, 0, 0);
#pragma unroll
        for (int t = 0; t < 8; ++t)
            acc[t] = __builtin_amdgcn_mfma_f32_16x16x32_bf16(a2l[kc], bh[t], acc[t], 0, 0, 0);
#pragma unroll
        for (int t = 0; t < 8; ++t)
            acc[t] = __builtin_amdgcn_mfma_f32_16x16x32_bf16(a2h[kc], bl[t], acc[t], 0, 0, 0);
    }

    const int orow0 = base + w * 16 + lq * 4;
#pragma unroll
    for (int t = 0; t < 8; ++t) {
        const int col = t * 16 + l15;
        const float bias = B1[col] + B2[col];
#pragma unroll
        for (int r = 0; r < 4; ++r) {
            const int grow = orow0 + r;
            if (grow >= N) continue;
            out[(size_t)grow * DD + col] = fmaxf(acc[t][r] + bias, 0.f);
        }
    }
}

// ---------------- host launch ----------------

extern "C" void kernel_launch(void* const* d_in, const int* in_sizes, int n_in,
                              void* d_out, int out_size, void* d_ws, size_t ws_size,
                              hipStream_t stream) {
    const float* emb_user = (const float*)d_in[0];
    const float* emb_item = (const float*)d_in[1];
    const float* head_W   = (const float*)d_in[26];
    const float* head_b   = (const float*)d_in[27];
    const int*   ue_src   = (const int*)d_in[28];
    const int*   ue_dst   = (const int*)d_in[29];
    const int*   iu_src   = (const int*)d_in[30];
    const int*   iu_dst   = (const int*)d_in[31];

    const int NU = in_sizes[0] / DD;
    const int NI = in_sizes[1] / DD;
    const int E  = in_sizes[28];

    const float* L[2][12];
    for (int l = 0; l < 2; ++l)
        for (int j = 0; j < 12; ++j) L[l][j] = (const float*)d_in[2 + l * 12 + j];

    // ---- workspace carve-up ----
    const size_t SU = (size_t)NU * DD, SI = (size_t)NI * DD;
    const size_t WPLANE = 12 * (size_t)DD * DD;
    size_t need = 0;
    auto pad256 = [](size_t b) { return (b + 255) & ~(size_t)255; };
    need += 2 * pad256(SU * 4) + 2 * pad256(SI * 4);
    need += pad256((size_t)NI * 4) + pad256((size_t)NU * 4);
    need += pad256((size_t)NI * PAD_I * 4) + pad256((size_t)NU * PAD_U * 4);
    need += 2 * pad256(WPLANE * 2);
    if (ws_size < need) return;  // fail via absmax instead of faulting

    char* w = (char*)d_ws;
    auto alloc = [&](size_t bytes) { void* p = w; w += pad256(bytes); return p; };
    float* Ua    = (float*)alloc(SU * 4);
    float* Ub    = (float*)alloc(SU * 4);
    float* Ia    = (float*)alloc(SI * 4);
    float* Ib    = (float*)alloc(SI * 4);
    int*   deg_i = (int*)alloc((size_t)NI * 4);
    int*   deg_u = (int*)alloc((size_t)NU * 4);
    int*   adj_i = (int*)alloc((size_t)NI * PAD_I * 4);
    int*   adj_u = (int*)alloc((size_t)NU * PAD_U * 4);
    unsigned short* Whi = (unsigned short*)alloc(WPLANE * 2);
    unsigned short* Wlo = (unsigned short*)alloc(WPLANE * 2);

    auto cdiv = [](long long a, long long b) { return (int)((a + b - 1) / b); };

    // pre-split + pack weights; plane order per layer l (base l*6): pW1, pW2, uiWn, uiWs, iuWn, iuWs
    W12 ws;
    for (int l = 0; l < 2; ++l) {
        ws.p[l * 6 + 0] = L[l][0];
        ws.p[l * 6 + 1] = L[l][2];
        ws.p[l * 6 + 2] = L[l][4];
        ws.p[l * 6 + 3] = L[l][6];
        ws.p[l * 6 + 4] = L[l][8];
        ws.p[l * 6 + 5] = L[l][10];
    }
    wsplit_k<<<cdiv(WPLANE, 256), 256, 0, stream>>>(ws, Whi, Wlo);

    // padded adjacency (layer-invariant)
    zeroi_k<<<cdiv(NI, 256), 256, 0, stream>>>(deg_i, NI);
    zeroi_k<<<cdiv(NU, 256), 256, 0, stream>>>(deg_u, NU);
    fill_k<<<cdiv(E, 256), 256, 0, stream>>>(ue_src, ue_dst, deg_i, adj_i, PAD_I, E);
    fill_k<<<cdiv(E, 256), 256, 0, stream>>>(iu_src, iu_dst, deg_u, adj_u, PAD_U, E);

    const int gI = cdiv(NI, 64), gU = cdiv(NU, 64);
    const size_t WM = (size_t)DD * DD;
    auto WH = [&](int l, int m) { return Whi + ((size_t)l * 6 + m) * WM; };
    auto WL = [&](int l, int m) { return Wlo + ((size_t)l * 6 + m) * WM; };

    // ---------------- layer 1 (relu applied at load from raw embeddings) ----------------
    // Ia = gather-mean(relu emb_user over adj_i) - (relu(emb_item)@pW1->relu->@pW2 + b2)*mask
    fused23g_k<true, true><<<gI, 256, 0, stream>>>(
        emb_item, WH(0,0), WL(0,0), L[0][1], WH(0,1), WL(0,1), L[0][3],
        emb_user, adj_i, PAD_I, deg_i, Ia, NI);
    // xi1 (Ia) = relu(Ia@uiWn + uibn + relu(emb_item)@uiWs + uibs)
    gemm_dual_k<true><<<gI, 256, 0, stream>>>(Ia, WH(0,2), WL(0,2), L[0][5],
                                              emb_item, WH(0,3), WL(0,3), L[0][7], Ia, NI);
    // xu1 (Ua) = relu(gather-mean(relu emb_item over adj_u)@iuWn + iubn + relu(emb_user)@iuWs + iubs)
    dualg_k<true, true><<<gU, 256, 0, stream>>>(
        emb_item, adj_u, PAD_U, deg_u, WH(0,4), WL(0,4), L[0][9],
        emb_user, WH(0,5), WL(0,5), L[0][11], Ua, NU);

    // ---------------- layer 2 ----------------
    fused23g_k<false, false><<<gI, 256, 0, stream>>>(
        Ia, WH(1,0), WL(1,0), L[1][1], WH(1,1), WL(1,1), L[1][3],
        Ua, adj_i, PAD_I, deg_i, Ib, NI);
    gemm_dual_k<false><<<gI, 256, 0, stream>>>(Ib, WH(1,2), WL(1,2), L[1][5],
                                               Ia, WH(1,3), WL(1,3), L[1][7], Ib, NI);
    dualg_k<false, false><<<gU, 256, 0, stream>>>(
        Ia, adj_u, PAD_U, deg_u, WH(1,4), WL(1,4), L[1][9],
        Ua, WH(1,5), WL(1,5), L[1][11], Ub, NU);

    head_k<<<cdiv(NU, 4), 256, 0, stream>>>(Ub, head_W, head_b, (float*)d_out, NU);
}

// Round 12
// 597.098 us; speedup vs baseline: 1.2441x; 1.2441x over previous
//
#include <hip/hip_runtime.h>

#define DD 128      // feature dim
#define PAD_I 64    // max item in-degree (Poisson(16); P(overflow) ~ 1e-6, guarded)
#define PAD_U 48    // max user in-degree (Poisson(8);  P(overflow) ~ 1e-9, guarded)

typedef __attribute__((ext_vector_type(8))) short bf16x8;
typedef __attribute__((ext_vector_type(4))) float f32x4;

// RNE fp32 -> bf16 split: x ~= hi + lo with |x - hi - lo| <= 2^-18 |x|
__device__ __forceinline__ void split2(float x, unsigned short& h, unsigned short& l) {
    unsigned int u = __float_as_uint(x);
    unsigned int hb = (u + 0x7FFFu + ((u >> 16) & 1u)) >> 16;
    h = (unsigned short)hb;
    float r = x - __uint_as_float(hb << 16);
    unsigned int v = __float_as_uint(r);
    l = (unsigned short)((v + 0x7FFFu + ((v >> 16) & 1u)) >> 16);
}

// load 8 contiguous fp32 (optionally relu) and split into hi/lo bf16 frags
template <bool R>
__device__ __forceinline__ void load_split8(const float* __restrict__ p,
                                            bf16x8& hf, bf16x8& lf) {
    float4 v0 = *reinterpret_cast<const float4*>(p);
    float4 v1 = *reinterpret_cast<const float4*>(p + 4);
    float x[8] = {v0.x, v0.y, v0.z, v0.w, v1.x, v1.y, v1.z, v1.w};
#pragma unroll
    for (int j = 0; j < 8; ++j) {
        float xv = R ? fmaxf(x[j], 0.f) : x[j];
        unsigned short h, l;
        split2(xv, h, l);
        hf[j] = (short)h;
        lf[j] = (short)l;
    }
}

// ---------------- misc kernels ----------------

__global__ __launch_bounds__(256) void zeroi_k(int* __restrict__ p, int n) {
    int gid = blockIdx.x * 256 + threadIdx.x;
    if (gid < n) p[gid] = 0;
}

__global__ __launch_bounds__(256) void fill_k(const int* __restrict__ src,
                                              const int* __restrict__ dst,
                                              int* __restrict__ cur,
                                              int* __restrict__ pad, int PAD, int E) {
    int e = blockIdx.x * 256 + threadIdx.x;
    if (e >= E) return;
    int d = dst[e];
    int slot = atomicAdd(&cur[d], 1);
    if (slot < PAD) pad[(size_t)d * PAD + slot] = src[e];
}

// out[row][:] = mean over adjacency of (relu?) feat[src][:]   (r10-verified)
// 1 wave per row; 32 lanes x float4 per edge, DIRECT pl[j] index loads,
// 2 edges in flight: pairs (j, j+2) stride 4 + guarded tail.
template <bool RELU>
__global__ __launch_bounds__(256) void gather_mean_k(const float* __restrict__ feat,
                                                     const int* __restrict__ cur,
                                                     const int* __restrict__ pad, int PAD,
                                                     float* __restrict__ out, int N) {
    int row = blockIdx.x * 4 + (threadIdx.x >> 6);
    if (row >= N) return;
    int lane = threadIdx.x & 63;
    int p = lane >> 5, c = lane & 31;
    int deg = cur[row]; if (deg > PAD) deg = PAD;
    const int* pl = pad + (size_t)row * PAD;

    float4 a0 = make_float4(0.f, 0.f, 0.f, 0.f);
    float4 a1 = make_float4(0.f, 0.f, 0.f, 0.f);
    int j = p;
    for (; j + 2 < deg; j += 4) {
        int s0 = pl[j];
        int s1 = pl[j + 2];
        float4 v0 = *reinterpret_cast<const float4*>(feat + (size_t)s0 * DD + c * 4);
        float4 v1 = *reinterpret_cast<const float4*>(feat + (size_t)s1 * DD + c * 4);
        if (RELU) {
            v0.x = fmaxf(v0.x, 0.f); v0.y = fmaxf(v0.y, 0.f);
            v0.z = fmaxf(v0.z, 0.f); v0.w = fmaxf(v0.w, 0.f);
            v1.x = fmaxf(v1.x, 0.f); v1.y = fmaxf(v1.y, 0.f);
            v1.z = fmaxf(v1.z, 0.f); v1.w = fmaxf(v1.w, 0.f);
        }
        a0.x += v0.x; a0.y += v0.y; a0.z += v0.z; a0.w += v0.w;
        a1.x += v1.x; a1.y += v1.y; a1.z += v1.z; a1.w += v1.w;
    }
    if (j < deg) {
        int s = pl[j];
        float4 v = *reinterpret_cast<const float4*>(feat + (size_t)s * DD + c * 4);
        if (RELU) {
            v.x = fmaxf(v.x, 0.f); v.y = fmaxf(v.y, 0.f);
            v.z = fmaxf(v.z, 0.f); v.w = fmaxf(v.w, 0.f);
        }
        a0.x += v.x; a0.y += v.y; a0.z += v.z; a0.w += v.w;
    }
    a0.x += a1.x; a0.y += a1.y; a0.z += a1.z; a0.w += a1.w;

    a0.x += __shfl_xor(a0.x, 32);
    a0.y += __shfl_xor(a0.y, 32);
    a0.z += __shfl_xor(a0.z, 32);
    a0.w += __shfl_xor(a0.w, 32);
    if (p == 0) {
        float iv = 1.0f / (float)(deg > 1 ? deg : 1);
        a0.x *= iv; a0.y *= iv; a0.z *= iv; a0.w *= iv;
        *reinterpret_cast<float4*>(out + (size_t)row * DD + c * 4) = a0;
    }
}

// out[n] = dot(x[n][:], hw) + hb
__global__ __launch_bounds__(256) void head_k(const float* __restrict__ x,
                                              const float* __restrict__ hw,
                                              const float* __restrict__ hb,
                                              float* __restrict__ out, int N) {
    int wid = threadIdx.x >> 6, lane = threadIdx.x & 63;
    int row = blockIdx.x * 4 + wid;
    if (row >= N) return;
    const float* xr = x + (size_t)row * DD;
    float v = xr[lane] * hw[lane] + xr[lane + 64] * hw[lane + 64];
    for (int off = 32; off > 0; off >>= 1) v += __shfl_down(v, off);
    if (lane == 0) out[row] = v + hb[0];
}

// ---------------- weight pre-split into PACKED fragment-order bf16 planes ----------------
// Packed p = ((kc*8 + t)*64 + lane)*8 + j  <->  W[t*16 + (lane&15)][kc*32 + (lane>>4)*8 + j]

struct W12 { const float* p[12]; };

__global__ __launch_bounds__(256) void wsplit_k(W12 ws, unsigned short* __restrict__ hi,
                                                unsigned short* __restrict__ lo) {
    int idx = blockIdx.x * 256 + threadIdx.x;
    if (idx >= 12 * DD * DD) return;
    int m = idx >> 14, pk = idx & 16383;
    int j = pk & 7, lane = (pk >> 3) & 63, t = (pk >> 9) & 7, kc = (pk >> 12) & 3;
    int src = (t * 16 + (lane & 15)) * DD + kc * 32 + (lane >> 4) * 8 + j;
    unsigned short h, l;
    split2(ws.p[m][src], h, l);
    hi[idx] = h;
    lo[idx] = l;
}

// ---------------- split-bf16 MFMA GEMM kernels — COLUMN-SPLIT waves ----------------
// FULL 3-product split: ah*bh + al*bh + ah*bl (~2^-18 residual).
// mfma_f32_16x16x32_bf16: A/B row = lane&15, k = (lane>>4)*8 + j; C/D col = lane&15,
// row = (lane>>4)*4 + reg.
// Block = 32 rows x 128 cols, 4 waves: wave w -> rowgroup rg=w>>1 (16 rows),
// colhalf cg=w&1 (64 cols, t' = cg*4+t).  Halves per-wave chain and VGPR vs r10.

// fused steps 2+3: h = relu(X@W1^T+b1) block-local FP32 in LDS; Io -= (h@W2^T + b2)*(deg>0)
template <bool RELX>
__global__ __launch_bounds__(256) void fused23_k(
        const float* __restrict__ X,
        const unsigned short* __restrict__ W1h, const unsigned short* __restrict__ W1l,
        const float* __restrict__ B1,
        const unsigned short* __restrict__ W2h, const unsigned short* __restrict__ W2l,
        const float* __restrict__ B2,
        float* __restrict__ Io, int N, const int* __restrict__ deg) {
    __shared__ __align__(16) float hl[32][DD + 4];   // stride 132 f = 528B

    const int tid = threadIdx.x;
    const int w = tid >> 6, l = tid & 63;
    const int rg = w >> 1, cg = w & 1;
    const int l15 = l & 15, lq = l >> 4;
    const int base = blockIdx.x * 32;

    const int rowA = base + rg * 16 + l15;
    const int rA = rowA < N ? rowA : N - 1;
    const float* xp = X + (size_t)rA * DD;

    bf16x8 ah[4], al[4];
#pragma unroll
    for (int kc = 0; kc < 4; ++kc)
        load_split8<RELX>(xp + kc * 32 + lq * 8, ah[kc], al[kc]);

    f32x4 acc[4];
#pragma unroll
    for (int t = 0; t < 4; ++t) acc[t] = (f32x4){0.f, 0.f, 0.f, 0.f};

#pragma unroll
    for (int kc = 0; kc < 4; ++kc) {
        const size_t fb = ((size_t)(kc * 8 + cg * 4) * 64 + l) * 8;
        bf16x8 bh[4], bl[4];
#pragma unroll
        for (int t = 0; t < 4; ++t) bh[t] = *reinterpret_cast<const bf16x8*>(W1h + fb + t * 512);
#pragma unroll
        for (int t = 0; t < 4; ++t) bl[t] = *reinterpret_cast<const bf16x8*>(W1l + fb + t * 512);
#pragma unroll
        for (int t = 0; t < 4; ++t)
            acc[t] = __builtin_amdgcn_mfma_f32_16x16x32_bf16(ah[kc], bh[t], acc[t], 0, 0, 0);
#pragma unroll
        for (int t = 0; t < 4; ++t)
            acc[t] = __builtin_amdgcn_mfma_f32_16x16x32_bf16(al[kc], bh[t], acc[t], 0, 0, 0);
#pragma unroll
        for (int t = 0; t < 4; ++t)
            acc[t] = __builtin_amdgcn_mfma_f32_16x16x32_bf16(ah[kc], bl[t], acc[t], 0, 0, 0);
    }

    // h = relu(acc + b1) -> LDS fp32 (C/D layout rows rg*16+lq*4+r, cols cg*64..)
    const int lr0 = rg * 16 + lq * 4;
#pragma unroll
    for (int t = 0; t < 4; ++t) {
        const int col = (cg * 4 + t) * 16 + l15;
        const float b = B1[col];
#pragma unroll
        for (int r = 0; r < 4; ++r)
            hl[lr0 + r][col] = fmaxf(acc[t][r] + b, 0.f);
    }
    __syncthreads();

    // read h back in A-frag layout + split (full row; other colhalf supplied via barrier)
    bf16x8 ah2[4], al2[4];
#pragma unroll
    for (int kc = 0; kc < 4; ++kc)
        load_split8<false>(&hl[rg * 16 + l15][kc * 32 + lq * 8], ah2[kc], al2[kc]);

#pragma unroll
    for (int t = 0; t < 4; ++t) acc[t] = (f32x4){0.f, 0.f, 0.f, 0.f};

#pragma unroll
    for (int kc = 0; kc < 4; ++kc) {
        const size_t fb = ((size_t)(kc * 8 + cg * 4) * 64 + l) * 8;
        bf16x8 bh[4], bl[4];
#pragma unroll
        for (int t = 0; t < 4; ++t) bh[t] = *reinterpret_cast<const bf16x8*>(W2h + fb + t * 512);
#pragma unroll
        for (int t = 0; t < 4; ++t) bl[t] = *reinterpret_cast<const bf16x8*>(W2l + fb + t * 512);
#pragma unroll
        for (int t = 0; t < 4; ++t)
            acc[t] = __builtin_amdgcn_mfma_f32_16x16x32_bf16(ah2[kc], bh[t], acc[t], 0, 0, 0);
#pragma unroll
        for (int t = 0; t < 4; ++t)
            acc[t] = __builtin_amdgcn_mfma_f32_16x16x32_bf16(al2[kc], bh[t], acc[t], 0, 0, 0);
#pragma unroll
        for (int t = 0; t < 4; ++t)
            acc[t] = __builtin_amdgcn_mfma_f32_16x16x32_bf16(ah2[kc], bl[t], acc[t], 0, 0, 0);
    }

    // epilogue: Io = Io - (acc + b2) * (deg>0)
#pragma unroll
    for (int t = 0; t < 4; ++t) {
        const int col = (cg * 4 + t) * 16 + l15;
        const float b2v = B2[col];
#pragma unroll
        for (int r = 0; r < 4; ++r) {
            const int grow = base + rg * 16 + lq * 4 + r;
            if (grow >= N) continue;
            float fl = deg[grow] > 0 ? 1.f : 0.f;
            float* op = Io + (size_t)grow * DD + col;
            *op = *op - (acc[t][r] + b2v) * fl;
        }
    }
}

// dual GEMM (32-row blocks, column-split): out = relu( X1@W1^T + b1 + X2@W2^T + b2 );
// out may alias X1 (each wave reads only the rows it writes; reads precede stores).
template <bool RELX2>
__global__ __launch_bounds__(256) void gemm_dual_k(
        const float* __restrict__ X1,
        const unsigned short* __restrict__ W1h, const unsigned short* __restrict__ W1l,
        const float* __restrict__ B1,
        const float* __restrict__ X2,
        const unsigned short* __restrict__ W2h, const unsigned short* __restrict__ W2l,
        const float* __restrict__ B2,
        float* __restrict__ out, int N) {
    const int tid = threadIdx.x;
    const int w = tid >> 6, l = tid & 63;
    const int rg = w >> 1, cg = w & 1;
    const int l15 = l & 15, lq = l >> 4;
    const int base = blockIdx.x * 32;

    const int rowA = base + rg * 16 + l15;
    const int rA = rowA < N ? rowA : N - 1;

    f32x4 acc[4];
#pragma unroll
    for (int t = 0; t < 4; ++t) acc[t] = (f32x4){0.f, 0.f, 0.f, 0.f};

    {
        bf16x8 ah[4], al[4];
#pragma unroll
        for (int kc = 0; kc < 4; ++kc)
            load_split8<false>(X1 + (size_t)rA * DD + kc * 32 + lq * 8, ah[kc], al[kc]);
#pragma unroll
        for (int kc = 0; kc < 4; ++kc) {
            const size_t fb = ((size_t)(kc * 8 + cg * 4) * 64 + l) * 8;
            bf16x8 bh[4], bl[4];
#pragma unroll
            for (int t = 0; t < 4; ++t) bh[t] = *reinterpret_cast<const bf16x8*>(W1h + fb + t * 512);
#pragma unroll
            for (int t = 0; t < 4; ++t) bl[t] = *reinterpret_cast<const bf16x8*>(W1l + fb + t * 512);
#pragma unroll
            for (int t = 0; t < 4; ++t)
                acc[t] = __builtin_amdgcn_mfma_f32_16x16x32_bf16(ah[kc], bh[t], acc[t], 0, 0, 0);
#pragma unroll
            for (int t = 0; t < 4; ++t)
                acc[t] = __builtin_amdgcn_mfma_f32_16x16x32_bf16(al[kc], bh[t], acc[t], 0, 0, 0);
#pragma unroll
            for (int t = 0; t < 4; ++t)
                acc[t] = __builtin_amdgcn_mfma_f32_16x16x32_bf16(ah[kc], bl[t], acc[t], 0, 0, 0);
        }
    }
    {
        bf16x8 ah[4], al[4];
#pragma unroll
        for (int kc = 0; kc < 4; ++kc)
            load_split8<RELX2>(X2 + (size_t)rA * DD + kc * 32 + lq * 8, ah[kc], al[kc]);
#pragma unroll
        for (int kc = 0; kc < 4; ++kc) {
            const size_t fb = ((size_t)(kc * 8 + cg * 4) * 64 + l) * 8;
            bf16x8 bh[4], bl[4];
#pragma unroll
            for (int t = 0; t < 4; ++t) bh[t] = *reinterpret_cast<const bf16x8*>(W2h + fb + t * 512);
#pragma unroll
            for (int t = 0; t < 4; ++t) bl[t] = *reinterpret_cast<const bf16x8*>(W2l + fb + t * 512);
#pragma unroll
            for (int t = 0; t < 4; ++t)
                acc[t] = __builtin_amdgcn_mfma_f32_16x16x32_bf16(ah[kc], bh[t], acc[t], 0, 0, 0);
#pragma unroll
            for (int t = 0; t < 4; ++t)
                acc[t] = __builtin_amdgcn_mfma_f32_16x16x32_bf16(al[kc], bh[t], acc[t], 0, 0, 0);
#pragma unroll
            for (int t = 0; t < 4; ++t)
                acc[t] = __builtin_amdgcn_mfma_f32_16x16x32_bf16(ah[kc], bl[t], acc[t], 0, 0, 0);
        }
    }

#pragma unroll
    for (int t = 0; t < 4; ++t) {
        const int col = (cg * 4 + t) * 16 + l15;
        const float bias = B1[col] + B2[col];
#pragma unroll
        for (int r = 0; r < 4; ++r) {
            const int grow = base + rg * 16 + lq * 4 + r;
            if (grow >= N) continue;
            out[(size_t)grow * DD + col] = fmaxf(acc[t][r] + bias, 0.f);
        }
    }
}

// ---------------- host launch ----------------

extern "C" void kernel_launch(void* const* d_in, const int* in_sizes, int n_in,
                              void* d_out, int out_size, void* d_ws, size_t ws_size,
                              hipStream_t stream) {
    const float* emb_user = (const float*)d_in[0];
    const float* emb_item = (const float*)d_in[1];
    const float* head_W   = (const float*)d_in[26];
    const float* head_b   = (const float*)d_in[27];
    const int*   ue_src   = (const int*)d_in[28];
    const int*   ue_dst   = (const int*)d_in[29];
    const int*   iu_src   = (const int*)d_in[30];
    const int*   iu_dst   = (const int*)d_in[31];

    const int NU = in_sizes[0] / DD;
    const int NI = in_sizes[1] / DD;
    const int E  = in_sizes[28];

    const float* L[2][12];
    for (int l = 0; l < 2; ++l)
        for (int j = 0; j < 12; ++j) L[l][j] = (const float*)d_in[2 + l * 12 + j];

    // ---- workspace carve-up ----
    const size_t SU = (size_t)NU * DD, SI = (size_t)NI * DD;
    const size_t WPLANE = 12 * (size_t)DD * DD;
    size_t need = 0;
    auto pad256 = [](size_t b) { return (b + 255) & ~(size_t)255; };
    need += 2 * pad256(SU * 4) + 2 * pad256(SI * 4);
    need += pad256((size_t)NI * 4) + pad256((size_t)NU * 4);
    need += pad256((size_t)NI * PAD_I * 4) + pad256((size_t)NU * PAD_U * 4);
    need += 2 * pad256(WPLANE * 2);
    if (ws_size < need) return;  // fail via absmax instead of faulting

    char* w = (char*)d_ws;
    auto alloc = [&](size_t bytes) { void* p = w; w += pad256(bytes); return p; };
    float* Ua    = (float*)alloc(SU * 4);
    float* Ub    = (float*)alloc(SU * 4);
    float* Ia    = (float*)alloc(SI * 4);
    float* Ib    = (float*)alloc(SI * 4);
    int*   deg_i = (int*)alloc((size_t)NI * 4);
    int*   deg_u = (int*)alloc((size_t)NU * 4);
    int*   adj_i = (int*)alloc((size_t)NI * PAD_I * 4);
    int*   adj_u = (int*)alloc((size_t)NU * PAD_U * 4);
    unsigned short* Whi = (unsigned short*)alloc(WPLANE * 2);
    unsigned short* Wlo = (unsigned short*)alloc(WPLANE * 2);

    auto cdiv = [](long long a, long long b) { return (int)((a + b - 1) / b); };

    // pre-split + pack weights; plane order per layer l (base l*6): pW1, pW2, uiWn, uiWs, iuWn, iuWs
    W12 ws;
    for (int l = 0; l < 2; ++l) {
        ws.p[l * 6 + 0] = L[l][0];
        ws.p[l * 6 + 1] = L[l][2];
        ws.p[l * 6 + 2] = L[l][4];
        ws.p[l * 6 + 3] = L[l][6];
        ws.p[l * 6 + 4] = L[l][8];
        ws.p[l * 6 + 5] = L[l][10];
    }
    wsplit_k<<<cdiv(WPLANE, 256), 256, 0, stream>>>(ws, Whi, Wlo);

    // padded adjacency (layer-invariant)
    zeroi_k<<<cdiv(NI, 256), 256, 0, stream>>>(deg_i, NI);
    zeroi_k<<<cdiv(NU, 256), 256, 0, stream>>>(deg_u, NU);
    fill_k<<<cdiv(E, 256), 256, 0, stream>>>(ue_src, ue_dst, deg_i, adj_i, PAD_I, E);
    fill_k<<<cdiv(E, 256), 256, 0, stream>>>(iu_src, iu_dst, deg_u, adj_u, PAD_U, E);

    const int gI = cdiv(NI, 32), gU = cdiv(NU, 32);
    const size_t WM = (size_t)DD * DD;
    auto WH = [&](int l, int m) { return Whi + ((size_t)l * 6 + m) * WM; };
    auto WL = [&](int l, int m) { return Wlo + ((size_t)l * 6 + m) * WM; };

    // ---------------- layer 1 (relu applied at load from raw embeddings) ----------------
    gather_mean_k<true><<<cdiv(NI, 4), 256, 0, stream>>>(emb_user, deg_i, adj_i, PAD_I, Ia, NI);
    fused23_k<true><<<gI, 256, 0, stream>>>(emb_item, WH(0,0), WL(0,0), L[0][1],
                                            WH(0,1), WL(0,1), L[0][3], Ia, NI, deg_i);
    gemm_dual_k<true><<<gI, 256, 0, stream>>>(Ia, WH(0,2), WL(0,2), L[0][5],
                                              emb_item, WH(0,3), WL(0,3), L[0][7], Ia, NI);
    gather_mean_k<true><<<cdiv(NU, 4), 256, 0, stream>>>(emb_item, deg_u, adj_u, PAD_U, Ua, NU);
    gemm_dual_k<true><<<gU, 256, 0, stream>>>(Ua, WH(0,4), WL(0,4), L[0][9],
                                              emb_user, WH(0,5), WL(0,5), L[0][11], Ua, NU);

    // ---------------- layer 2 ----------------
    gather_mean_k<false><<<cdiv(NI, 4), 256, 0, stream>>>(Ua, deg_i, adj_i, PAD_I, Ib, NI);
    fused23_k<false><<<gI, 256, 0, stream>>>(Ia, WH(1,0), WL(1,0), L[1][1],
                                             WH(1,1), WL(1,1), L[1][3], Ib, NI, deg_i);
    gemm_dual_k<false><<<gI, 256, 0, stream>>>(Ib, WH(1,2), WL(1,2), L[1][5],
                                               Ia, WH(1,3), WL(1,3), L[1][7], Ib, NI);
    gather_mean_k<false><<<cdiv(NU, 4), 256, 0, stream>>>(Ia, deg_u, adj_u, PAD_U, Ub, NU);
    gemm_dual_k<false><<<gU, 256, 0, stream>>>(Ub, WH(1,4), WL(1,4), L[1][9],
                                               Ua, WH(1,5), WL(1,5), L[1][11], Ub, NU);

    head_k<<<cdiv(NU, 4), 256, 0, stream>>>(Ub, head_W, head_b, (float*)d_out, NU);
}

// Round 13
// 576.167 us; speedup vs baseline: 1.2893x; 1.0363x over previous
//
#include <hip/hip_runtime.h>
#include <hip/hip_bf16.h>

#define DD 128      // feature dim
#define PAD_I 64    // max item in-degree (Poisson(16); P(overflow) ~ 1e-6, guarded)
#define PAD_U 48    // max user in-degree (Poisson(8);  P(overflow) ~ 1e-9, guarded)

typedef __attribute__((ext_vector_type(8))) short bf16x8;
typedef __attribute__((ext_vector_type(4))) float f32x4;

// manual RNE fp32 -> bf16 (one-time weight prep only)
__device__ __forceinline__ unsigned short rne_bf16(float x) {
    unsigned int u = __float_as_uint(x);
    return (unsigned short)((u + 0x7FFFu + ((u >> 16) & 1u)) >> 16);
}

// load 8 contiguous fp32 (optionally relu) -> hi+lo bf16 frags.
// Pairwise via __float22bfloat162_rn so the compiler emits v_cvt_pk_bf16_f32
// (~4x fewer VALU ops than the manual bit-twiddle). Rounding is bit-identical
// to the manual RNE split (hi = RNE(x), lo = RNE(x - hi)).
template <bool R>
__device__ __forceinline__ void load_split8(const float* __restrict__ p,
                                            bf16x8& hf, bf16x8& lf) {
    float4 v0 = *reinterpret_cast<const float4*>(p);
    float4 v1 = *reinterpret_cast<const float4*>(p + 4);
    float x[8] = {v0.x, v0.y, v0.z, v0.w, v1.x, v1.y, v1.z, v1.w};
#pragma unroll
    for (int j = 0; j < 8; j += 2) {
        float a = R ? fmaxf(x[j], 0.f) : x[j];
        float b = R ? fmaxf(x[j + 1], 0.f) : x[j + 1];
        __hip_bfloat162 h2 = __float22bfloat162_rn(make_float2(a, b));
        float2 hr = __bfloat1622float2(h2);
        __hip_bfloat162 l2 = __float22bfloat162_rn(make_float2(a - hr.x, b - hr.y));
        hf[j]     = (short)__bfloat16_as_ushort(h2.x);
        hf[j + 1] = (short)__bfloat16_as_ushort(h2.y);
        lf[j]     = (short)__bfloat16_as_ushort(l2.x);
        lf[j + 1] = (short)__bfloat16_as_ushort(l2.y);
    }
}

// ---------------- misc kernels ----------------

__global__ __launch_bounds__(256) void zeroi_k(int* __restrict__ p, int n) {
    int gid = blockIdx.x * 256 + threadIdx.x;
    if (gid < n) p[gid] = 0;
}

__global__ __launch_bounds__(256) void fill_k(const int* __restrict__ src,
                                              const int* __restrict__ dst,
                                              int* __restrict__ cur,
                                              int* __restrict__ pad, int PAD, int E) {
    int e = blockIdx.x * 256 + threadIdx.x;
    if (e >= E) return;
    int d = dst[e];
    int slot = atomicAdd(&cur[d], 1);
    if (slot < PAD) pad[(size_t)d * PAD + slot] = src[e];
}

// out[row][:] = mean over adjacency of (relu?) feat[src][:]   (r10-verified)
// 1 wave per row; 32 lanes x float4 per edge, DIRECT pl[j] index loads,
// 2 edges in flight: pairs (j, j+2) stride 4 + guarded tail.
template <bool RELU>
__global__ __launch_bounds__(256) void gather_mean_k(const float* __restrict__ feat,
                                                     const int* __restrict__ cur,
                                                     const int* __restrict__ pad, int PAD,
                                                     float* __restrict__ out, int N) {
    int row = blockIdx.x * 4 + (threadIdx.x >> 6);
    if (row >= N) return;
    int lane = threadIdx.x & 63;
    int p = lane >> 5, c = lane & 31;
    int deg = cur[row]; if (deg > PAD) deg = PAD;
    const int* pl = pad + (size_t)row * PAD;

    float4 a0 = make_float4(0.f, 0.f, 0.f, 0.f);
    float4 a1 = make_float4(0.f, 0.f, 0.f, 0.f);
    int j = p;
    for (; j + 2 < deg; j += 4) {
        int s0 = pl[j];
        int s1 = pl[j + 2];
        float4 v0 = *reinterpret_cast<const float4*>(feat + (size_t)s0 * DD + c * 4);
        float4 v1 = *reinterpret_cast<const float4*>(feat + (size_t)s1 * DD + c * 4);
        if (RELU) {
            v0.x = fmaxf(v0.x, 0.f); v0.y = fmaxf(v0.y, 0.f);
            v0.z = fmaxf(v0.z, 0.f); v0.w = fmaxf(v0.w, 0.f);
            v1.x = fmaxf(v1.x, 0.f); v1.y = fmaxf(v1.y, 0.f);
            v1.z = fmaxf(v1.z, 0.f); v1.w = fmaxf(v1.w, 0.f);
        }
        a0.x += v0.x; a0.y += v0.y; a0.z += v0.z; a0.w += v0.w;
        a1.x += v1.x; a1.y += v1.y; a1.z += v1.z; a1.w += v1.w;
    }
    if (j < deg) {
        int s = pl[j];
        float4 v = *reinterpret_cast<const float4*>(feat + (size_t)s * DD + c * 4);
        if (RELU) {
            v.x = fmaxf(v.x, 0.f); v.y = fmaxf(v.y, 0.f);
            v.z = fmaxf(v.z, 0.f); v.w = fmaxf(v.w, 0.f);
        }
        a0.x += v.x; a0.y += v.y; a0.z += v.z; a0.w += v.w;
    }
    a0.x += a1.x; a0.y += a1.y; a0.z += a1.z; a0.w += a1.w;

    a0.x += __shfl_xor(a0.x, 32);
    a0.y += __shfl_xor(a0.y, 32);
    a0.z += __shfl_xor(a0.z, 32);
    a0.w += __shfl_xor(a0.w, 32);
    if (p == 0) {
        float iv = 1.0f / (float)(deg > 1 ? deg : 1);
        a0.x *= iv; a0.y *= iv; a0.z *= iv; a0.w *= iv;
        *reinterpret_cast<float4*>(out + (size_t)row * DD + c * 4) = a0;
    }
}

// out[n] = dot(x[n][:], hw) + hb
__global__ __launch_bounds__(256) void head_k(const float* __restrict__ x,
                                              const float* __restrict__ hw,
                                              const float* __restrict__ hb,
                                              float* __restrict__ out, int N) {
    int wid = threadIdx.x >> 6, lane = threadIdx.x & 63;
    int row = blockIdx.x * 4 + wid;
    if (row >= N) return;
    const float* xr = x + (size_t)row * DD;
    float v = xr[lane] * hw[lane] + xr[lane + 64] * hw[lane + 64];
    for (int off = 32; off > 0; off >>= 1) v += __shfl_down(v, off);
    if (lane == 0) out[row] = v + hb[0];
}

// ---------------- weight pre-split into PACKED fragment-order bf16 planes ----------------
// Packed p = ((kc*8 + t)*64 + lane)*8 + j  <->  W[t*16 + (lane&15)][kc*32 + (lane>>4)*8 + j]

struct W12 { const float* p[12]; };

__global__ __launch_bounds__(256) void wsplit_k(W12 ws, unsigned short* __restrict__ hi,
                                                unsigned short* __restrict__ lo) {
    int idx = blockIdx.x * 256 + threadIdx.x;
    if (idx >= 12 * DD * DD) return;
    int m = idx >> 14, pk = idx & 16383;
    int j = pk & 7, lane = (pk >> 3) & 63, t = (pk >> 9) & 7, kc = (pk >> 12) & 3;
    int src = (t * 16 + (lane & 15)) * DD + kc * 32 + (lane >> 4) * 8 + j;
    float x = ws.p[m][src];
    unsigned short h = rne_bf16(x);
    float r = x - __uint_as_float((unsigned int)h << 16);
    hi[idx] = h;
    lo[idx] = rne_bf16(r);
}

// ---------------- split-bf16 MFMA GEMM kernels (r10 geometry) ----------------
// FULL 3-product split: ah*bh + al*bh + ah*bl (~2^-18 residual).
// mfma_f32_16x16x32_bf16: A/B row = lane&15, k = (lane>>4)*8 + j; C/D col = lane&15,
// row = (lane>>4)*4 + reg.  4 waves, 16 rows/wave, 64-row blocks.

// fused steps 2+3: h = relu(X@W1^T+b1) block-local FP32 in LDS; Io -= (h@W2^T + b2)*(deg>0)
template <bool RELX>
__global__ __launch_bounds__(256) void fused23_k(
        const float* __restrict__ X,
        const unsigned short* __restrict__ W1h, const unsigned short* __restrict__ W1l,
        const float* __restrict__ B1,
        const unsigned short* __restrict__ W2h, const unsigned short* __restrict__ W2l,
        const float* __restrict__ B2,
        float* __restrict__ Io, int N, const int* __restrict__ deg) {
    __shared__ __align__(16) float hl[64][DD + 4];   // stride 132 f = 528B

    const int tid = threadIdx.x;
    const int w = tid >> 6, l = tid & 63;
    const int l15 = l & 15, lq = l >> 4;

    const int rowA = blockIdx.x * 64 + w * 16 + l15;
    const int rA = rowA < N ? rowA : N - 1;
    const float* xp = X + (size_t)rA * DD;

    bf16x8 ah[4], al[4];
#pragma unroll
    for (int kc = 0; kc < 4; ++kc)
        load_split8<RELX>(xp + kc * 32 + lq * 8, ah[kc], al[kc]);

    f32x4 acc[8];
#pragma unroll
    for (int t = 0; t < 8; ++t) acc[t] = (f32x4){0.f, 0.f, 0.f, 0.f};

#pragma unroll
    for (int kc = 0; kc < 4; ++kc) {
        const size_t fb = ((size_t)(kc * 8) * 64 + l) * 8;
        bf16x8 bh[8], bl[8];
#pragma unroll
        for (int t = 0; t < 8; ++t) bh[t] = *reinterpret_cast<const bf16x8*>(W1h + fb + t * 512);
#pragma unroll
        for (int t = 0; t < 8; ++t) bl[t] = *reinterpret_cast<const bf16x8*>(W1l + fb + t * 512);
#pragma unroll
        for (int t = 0; t < 8; ++t)
            acc[t] = __builtin_amdgcn_mfma_f32_16x16x32_bf16(ah[kc], bh[t], acc[t], 0, 0, 0);
#pragma unroll
        for (int t = 0; t < 8; ++t)
            acc[t] = __builtin_amdgcn_mfma_f32_16x16x32_bf16(al[kc], bh[t], acc[t], 0, 0, 0);
#pragma unroll
        for (int t = 0; t < 8; ++t)
            acc[t] = __builtin_amdgcn_mfma_f32_16x16x32_bf16(ah[kc], bl[t], acc[t], 0, 0, 0);
    }

    // h = relu(acc + b1) -> LDS fp32 (C/D layout rows w*16+lq*4+r)
    const int lr0 = w * 16 + lq * 4;
#pragma unroll
    for (int t = 0; t < 8; ++t) {
        const int col = t * 16 + l15;
        const float b = B1[col];
#pragma unroll
        for (int r = 0; r < 4; ++r)
            hl[lr0 + r][col] = fmaxf(acc[t][r] + b, 0.f);
    }
    __syncthreads();

    // read h back in A-frag layout + split (full fidelity)
    bf16x8 ah2[4], al2[4];
#pragma unroll
    for (int kc = 0; kc < 4; ++kc)
        load_split8<false>(&hl[w * 16 + l15][kc * 32 + lq * 8], ah2[kc], al2[kc]);

#pragma unroll
    for (int t = 0; t < 8; ++t) acc[t] = (f32x4){0.f, 0.f, 0.f, 0.f};

#pragma unroll
    for (int kc = 0; kc < 4; ++kc) {
        const size_t fb = ((size_t)(kc * 8) * 64 + l) * 8;
        bf16x8 bh[8], bl[8];
#pragma unroll
        for (int t = 0; t < 8; ++t) bh[t] = *reinterpret_cast<const bf16x8*>(W2h + fb + t * 512);
#pragma unroll
        for (int t = 0; t < 8; ++t) bl[t] = *reinterpret_cast<const bf16x8*>(W2l + fb + t * 512);
#pragma unroll
        for (int t = 0; t < 8; ++t)
            acc[t] = __builtin_amdgcn_mfma_f32_16x16x32_bf16(ah2[kc], bh[t], acc[t], 0, 0, 0);
#pragma unroll
        for (int t = 0; t < 8; ++t)
            acc[t] = __builtin_amdgcn_mfma_f32_16x16x32_bf16(al2[kc], bh[t], acc[t], 0, 0, 0);
#pragma unroll
        for (int t = 0; t < 8; ++t)
            acc[t] = __builtin_amdgcn_mfma_f32_16x16x32_bf16(ah2[kc], bl[t], acc[t], 0, 0, 0);
    }

    // epilogue: Io = Io - (acc + b2) * (deg>0)
    const int orow0 = blockIdx.x * 64 + w * 16 + lq * 4;
#pragma unroll
    for (int t = 0; t < 8; ++t) {
        const int col = t * 16 + l15;
        const float b2v = B2[col];
#pragma unroll
        for (int r = 0; r < 4; ++r) {
            const int grow = orow0 + r;
            if (grow >= N) continue;
            float fl = deg[grow] > 0 ? 1.f : 0.f;
            float* op = Io + (size_t)grow * DD + col;
            *op = *op - (acc[t][r] + b2v) * fl;
        }
    }
}

// dual GEMM (64-row blocks, r10 geometry): out = relu( X1@W1^T + b1 + X2@W2^T + b2 );
// out may alias X1 (each wave reads only the rows it writes; reads precede stores).
template <bool RELX2>
__global__ __launch_bounds__(256) void gemm_dual_k(
        const float* __restrict__ X1,
        const unsigned short* __restrict__ W1h, const unsigned short* __restrict__ W1l,
        const float* __restrict__ B1,
        const float* __restrict__ X2,
        const unsigned short* __restrict__ W2h, const unsigned short* __restrict__ W2l,
        const float* __restrict__ B2,
        float* __restrict__ out, int N) {
    const int tid = threadIdx.x;
    const int w = tid >> 6, l = tid & 63;
    const int l15 = l & 15, lq = l >> 4;

    const int rowA = blockIdx.x * 64 + w * 16 + l15;
    const int rA = rowA < N ? rowA : N - 1;

    f32x4 acc[8];
#pragma unroll
    for (int t = 0; t < 8; ++t) acc[t] = (f32x4){0.f, 0.f, 0.f, 0.f};

    {
        bf16x8 ah[4], al[4];
#pragma unroll
        for (int kc = 0; kc < 4; ++kc)
            load_split8<false>(X1 + (size_t)rA * DD + kc * 32 + lq * 8, ah[kc], al[kc]);
#pragma unroll
        for (int kc = 0; kc < 4; ++kc) {
            const size_t fb = ((size_t)(kc * 8) * 64 + l) * 8;
            bf16x8 bh[8], bl[8];
#pragma unroll
            for (int t = 0; t < 8; ++t) bh[t] = *reinterpret_cast<const bf16x8*>(W1h + fb + t * 512);
#pragma unroll
            for (int t = 0; t < 8; ++t) bl[t] = *reinterpret_cast<const bf16x8*>(W1l + fb + t * 512);
#pragma unroll
            for (int t = 0; t < 8; ++t)
                acc[t] = __builtin_amdgcn_mfma_f32_16x16x32_bf16(ah[kc], bh[t], acc[t], 0, 0, 0);
#pragma unroll
            for (int t = 0; t < 8; ++t)
                acc[t] = __builtin_amdgcn_mfma_f32_16x16x32_bf16(al[kc], bh[t], acc[t], 0, 0, 0);
#pragma unroll
            for (int t = 0; t < 8; ++t)
                acc[t] = __builtin_amdgcn_mfma_f32_16x16x32_bf16(ah[kc], bl[t], acc[t], 0, 0, 0);
        }
    }
    {
        bf16x8 ah[4], al[4];
#pragma unroll
        for (int kc = 0; kc < 4; ++kc)
            load_split8<RELX2>(X2 + (size_t)rA * DD + kc * 32 + lq * 8, ah[kc], al[kc]);
#pragma unroll
        for (int kc = 0; kc < 4; ++kc) {
            const size_t fb = ((size_t)(kc * 8) * 64 + l) * 8;
            bf16x8 bh[8], bl[8];
#pragma unroll
            for (int t = 0; t < 8; ++t) bh[t] = *reinterpret_cast<const bf16x8*>(W2h + fb + t * 512);
#pragma unroll
            for (int t = 0; t < 8; ++t) bl[t] = *reinterpret_cast<const bf16x8*>(W2l + fb + t * 512);
#pragma unroll
            for (int t = 0; t < 8; ++t)
                acc[t] = __builtin_amdgcn_mfma_f32_16x16x32_bf16(ah[kc], bh[t], acc[t], 0, 0, 0);
#pragma unroll
            for (int t = 0; t < 8; ++t)
                acc[t] = __builtin_amdgcn_mfma_f32_16x16x32_bf16(al[kc], bh[t], acc[t], 0, 0, 0);
#pragma unroll
            for (int t = 0; t < 8; ++t)
                acc[t] = __builtin_amdgcn_mfma_f32_16x16x32_bf16(ah[kc], bl[t], acc[t], 0, 0, 0);
        }
    }

    const int orow0 = blockIdx.x * 64 + w * 16 + lq * 4;
#pragma unroll
    for (int t = 0; t < 8; ++t) {
        const int col = t * 16 + l15;
        const float bias = B1[col] + B2[col];
#pragma unroll
        for (int r = 0; r < 4; ++r) {
            const int grow = orow0 + r;
            if (grow >= N) continue;
            out[(size_t)grow * DD + col] = fmaxf(acc[t][r] + bias, 0.f);
        }
    }
}

// ---------------- host launch ----------------

extern "C" void kernel_launch(void* const* d_in, const int* in_sizes, int n_in,
                              void* d_out, int out_size, void* d_ws, size_t ws_size,
                              hipStream_t stream) {
    const float* emb_user = (const float*)d_in[0];
    const float* emb_item = (const float*)d_in[1];
    const float* head_W   = (const float*)d_in[26];
    const float* head_b   = (const float*)d_in[27];
    const int*   ue_src   = (const int*)d_in[28];
    const int*   ue_dst   = (const int*)d_in[29];
    const int*   iu_src   = (const int*)d_in[30];
    const int*   iu_dst   = (const int*)d_in[31];

    const int NU = in_sizes[0] / DD;
    const int NI = in_sizes[1] / DD;
    const int E  = in_sizes[28];

    const float* L[2][12];
    for (int l = 0; l < 2; ++l)
        for (int j = 0; j < 12; ++j) L[l][j] = (const float*)d_in[2 + l * 12 + j];

    // ---- workspace carve-up ----
    const size_t SU = (size_t)NU * DD, SI = (size_t)NI * DD;
    const size_t WPLANE = 12 * (size_t)DD * DD;
    size_t need = 0;
    auto pad256 = [](size_t b) { return (b + 255) & ~(size_t)255; };
    need += 2 * pad256(SU * 4) + 2 * pad256(SI * 4);
    need += pad256((size_t)NI * 4) + pad256((size_t)NU * 4);
    need += pad256((size_t)NI * PAD_I * 4) + pad256((size_t)NU * PAD_U * 4);
    need += 2 * pad256(WPLANE * 2);
    if (ws_size < need) return;  // fail via absmax instead of faulting

    char* w = (char*)d_ws;
    auto alloc = [&](size_t bytes) { void* p = w; w += pad256(bytes); return p; };
    float* Ua    = (float*)alloc(SU * 4);
    float* Ub    = (float*)alloc(SU * 4);
    float* Ia    = (float*)alloc(SI * 4);
    float* Ib    = (float*)alloc(SI * 4);
    int*   deg_i = (int*)alloc((size_t)NI * 4);
    int*   deg_u = (int*)alloc((size_t)NU * 4);
    int*   adj_i = (int*)alloc((size_t)NI * PAD_I * 4);
    int*   adj_u = (int*)alloc((size_t)NU * PAD_U * 4);
    unsigned short* Whi = (unsigned short*)alloc(WPLANE * 2);
    unsigned short* Wlo = (unsigned short*)alloc(WPLANE * 2);

    auto cdiv = [](long long a, long long b) { return (int)((a + b - 1) / b); };

    // pre-split + pack weights; plane order per layer l (base l*6): pW1, pW2, uiWn, uiWs, iuWn, iuWs
    W12 ws;
    for (int l = 0; l < 2; ++l) {
        ws.p[l * 6 + 0] = L[l][0];
        ws.p[l * 6 + 1] = L[l][2];
        ws.p[l * 6 + 2] = L[l][4];
        ws.p[l * 6 + 3] = L[l][6];
        ws.p[l * 6 + 4] = L[l][8];
        ws.p[l * 6 + 5] = L[l][10];
    }
    wsplit_k<<<cdiv(WPLANE, 256), 256, 0, stream>>>(ws, Whi, Wlo);

    // padded adjacency (layer-invariant)
    zeroi_k<<<cdiv(NI, 256), 256, 0, stream>>>(deg_i, NI);
    zeroi_k<<<cdiv(NU, 256), 256, 0, stream>>>(deg_u, NU);
    fill_k<<<cdiv(E, 256), 256, 0, stream>>>(ue_src, ue_dst, deg_i, adj_i, PAD_I, E);
    fill_k<<<cdiv(E, 256), 256, 0, stream>>>(iu_src, iu_dst, deg_u, adj_u, PAD_U, E);

    const int gI = cdiv(NI, 64), gU = cdiv(NU, 64);
    const size_t WM = (size_t)DD * DD;
    auto WH = [&](int l, int m) { return Whi + ((size_t)l * 6 + m) * WM; };
    auto WL = [&](int l, int m) { return Wlo + ((size_t)l * 6 + m) * WM; };

    // ---------------- layer 1 (relu applied at load from raw embeddings) ----------------
    gather_mean_k<true><<<cdiv(NI, 4), 256, 0, stream>>>(emb_user, deg_i, adj_i, PAD_I, Ia, NI);
    fused23_k<true><<<gI, 256, 0, stream>>>(emb_item, WH(0,0), WL(0,0), L[0][1],
                                            WH(0,1), WL(0,1), L[0][3], Ia, NI, deg_i);
    gemm_dual_k<true><<<gI, 256, 0, stream>>>(Ia, WH(0,2), WL(0,2), L[0][5],
                                              emb_item, WH(0,3), WL(0,3), L[0][7], Ia, NI);
    gather_mean_k<true><<<cdiv(NU, 4), 256, 0, stream>>>(emb_item, deg_u, adj_u, PAD_U, Ua, NU);
    gemm_dual_k<true><<<gU, 256, 0, stream>>>(Ua, WH(0,4), WL(0,4), L[0][9],
                                              emb_user, WH(0,5), WL(0,5), L[0][11], Ua, NU);

    // ---------------- layer 2 ----------------
    gather_mean_k<false><<<cdiv(NI, 4), 256, 0, stream>>>(Ua, deg_i, adj_i, PAD_I, Ib, NI);
    fused23_k<false><<<gI, 256, 0, stream>>>(Ia, WH(1,0), WL(1,0), L[1][1],
                                             WH(1,1), WL(1,1), L[1][3], Ib, NI, deg_i);
    gemm_dual_k<false><<<gI, 256, 0, stream>>>(Ib, WH(1,2), WL(1,2), L[1][5],
                                               Ia, WH(1,3), WL(1,3), L[1][7], Ib, NI);
    gather_mean_k<false><<<cdiv(NU, 4), 256, 0, stream>>>(Ia, deg_u, adj_u, PAD_U, Ub, NU);
    gemm_dual_k<false><<<gU, 256, 0, stream>>>(Ub, WH(1,4), WL(1,4), L[1][9],
                                               Ua, WH(1,5), WL(1,5), L[1][11], Ub, NU);

    head_k<<<cdiv(NU, 4), 256, 0, stream>>>(Ub, head_W, head_b, (float*)d_out, NU);
}

// Round 14
// 458.830 us; speedup vs baseline: 1.6190x; 1.2557x over previous
//
#include <hip/hip_runtime.h>
#include <hip/hip_bf16.h>

#define DD 128      // feature dim
#define PAD_I 64    // max item in-degree (Poisson(16); P(overflow) ~ 1e-6, guarded)
#define PAD_U 48    // max user in-degree (Poisson(8);  P(overflow) ~ 1e-9, guarded)

typedef __attribute__((ext_vector_type(8))) short bf16x8;
typedef __attribute__((ext_vector_type(4))) float f32x4;

// manual RNE fp32 -> bf16 (one-time weight prep only)
__device__ __forceinline__ unsigned short rne_bf16(float x) {
    unsigned int u = __float_as_uint(x);
    return (unsigned short)((u + 0x7FFFu + ((u >> 16) & 1u)) >> 16);
}

// load 8 contiguous fp32 (optionally relu) -> hi+lo bf16 frags (v_cvt_pk_bf16_f32 path)
template <bool R>
__device__ __forceinline__ void load_split8(const float* __restrict__ p,
                                            bf16x8& hf, bf16x8& lf) {
    float4 v0 = *reinterpret_cast<const float4*>(p);
    float4 v1 = *reinterpret_cast<const float4*>(p + 4);
    float x[8] = {v0.x, v0.y, v0.z, v0.w, v1.x, v1.y, v1.z, v1.w};
#pragma unroll
    for (int j = 0; j < 8; j += 2) {
        float a = R ? fmaxf(x[j], 0.f) : x[j];
        float b = R ? fmaxf(x[j + 1], 0.f) : x[j + 1];
        __hip_bfloat162 h2 = __float22bfloat162_rn(make_float2(a, b));
        float2 hr = __bfloat1622float2(h2);
        __hip_bfloat162 l2 = __float22bfloat162_rn(make_float2(a - hr.x, b - hr.y));
        hf[j]     = (short)__bfloat16_as_ushort(h2.x);
        hf[j + 1] = (short)__bfloat16_as_ushort(h2.y);
        lf[j]     = (short)__bfloat16_as_ushort(l2.x);
        lf[j + 1] = (short)__bfloat16_as_ushort(l2.y);
    }
}

// ---------------- misc kernels ----------------

__global__ __launch_bounds__(256) void zeroi_k(int* __restrict__ p, int n) {
    int gid = blockIdx.x * 256 + threadIdx.x;
    if (gid < n) p[gid] = 0;
}

__global__ __launch_bounds__(256) void fill_k(const int* __restrict__ src,
                                              const int* __restrict__ dst,
                                              int* __restrict__ cur,
                                              int* __restrict__ pad, int PAD, int E) {
    int e = blockIdx.x * 256 + threadIdx.x;
    if (e >= E) return;
    int d = dst[e];
    int slot = atomicAdd(&cur[d], 1);
    if (slot < PAD) pad[(size_t)d * PAD + slot] = src[e];
}

// r10-verified gather body (4 rows per block; 1 wave per row; 32 lanes x float4
// per edge, DIRECT pl[j] index loads, 2 edges in flight, xor-32 reduce).
template <bool RELU>
__device__ __forceinline__ void gather_body(const float* __restrict__ feat,
                                            const int* __restrict__ cur,
                                            const int* __restrict__ pad, int PAD,
                                            float* __restrict__ out, int N, int blk) {
    int row = blk * 4 + (threadIdx.x >> 6);
    if (row >= N) return;
    int lane = threadIdx.x & 63;
    int p = lane >> 5, c = lane & 31;
    int deg = cur[row]; if (deg > PAD) deg = PAD;
    const int* pl = pad + (size_t)row * PAD;

    float4 a0 = make_float4(0.f, 0.f, 0.f, 0.f);
    float4 a1 = make_float4(0.f, 0.f, 0.f, 0.f);
    int j = p;
    for (; j + 2 < deg; j += 4) {
        int s0 = pl[j];
        int s1 = pl[j + 2];
        float4 v0 = *reinterpret_cast<const float4*>(feat + (size_t)s0 * DD + c * 4);
        float4 v1 = *reinterpret_cast<const float4*>(feat + (size_t)s1 * DD + c * 4);
        if (RELU) {
            v0.x = fmaxf(v0.x, 0.f); v0.y = fmaxf(v0.y, 0.f);
            v0.z = fmaxf(v0.z, 0.f); v0.w = fmaxf(v0.w, 0.f);
            v1.x = fmaxf(v1.x, 0.f); v1.y = fmaxf(v1.y, 0.f);
            v1.z = fmaxf(v1.z, 0.f); v1.w = fmaxf(v1.w, 0.f);
        }
        a0.x += v0.x; a0.y += v0.y; a0.z += v0.z; a0.w += v0.w;
        a1.x += v1.x; a1.y += v1.y; a1.z += v1.z; a1.w += v1.w;
    }
    if (j < deg) {
        int s = pl[j];
        float4 v = *reinterpret_cast<const float4*>(feat + (size_t)s * DD + c * 4);
        if (RELU) {
            v.x = fmaxf(v.x, 0.f); v.y = fmaxf(v.y, 0.f);
            v.z = fmaxf(v.z, 0.f); v.w = fmaxf(v.w, 0.f);
        }
        a0.x += v.x; a0.y += v.y; a0.z += v.z; a0.w += v.w;
    }
    a0.x += a1.x; a0.y += a1.y; a0.z += a1.z; a0.w += a1.w;

    a0.x += __shfl_xor(a0.x, 32);
    a0.y += __shfl_xor(a0.y, 32);
    a0.z += __shfl_xor(a0.z, 32);
    a0.w += __shfl_xor(a0.w, 32);
    if (p == 0) {
        float iv = 1.0f / (float)(deg > 1 ? deg : 1);
        a0.x *= iv; a0.y *= iv; a0.z *= iv; a0.w *= iv;
        *reinterpret_cast<float4*>(out + (size_t)row * DD + c * 4) = a0;
    }
}

// standalone gather (L2 user gather)
template <bool RELU>
__global__ __launch_bounds__(256) void gather_mean_k(const float* __restrict__ feat,
                                                     const int* __restrict__ cur,
                                                     const int* __restrict__ pad, int PAD,
                                                     float* __restrict__ out, int N) {
    gather_body<RELU>(feat, cur, pad, PAD, out, N, blockIdx.x);
}

// merged dual gather (L1): task1 (nb1 blocks) + task2 (nb2 blocks), block-striped
// 1:2 when nb2==2*nb1 (our shape) so both traffic streams mix on the fabric.
template <bool RELU1, bool RELU2>
__global__ __launch_bounds__(256) void gather2_k(
        const float* __restrict__ feat1, const int* __restrict__ cur1,
        const int* __restrict__ pad1, int PAD1, float* __restrict__ out1, int N1, int nb1,
        const float* __restrict__ feat2, const int* __restrict__ cur2,
        const int* __restrict__ pad2, int PAD2, float* __restrict__ out2, int N2, int nb2) {
    int b = blockIdx.x;
    int which, idx;
    if (nb2 == 2 * nb1) {               // exact 1:2 stripe: b%3==0 -> task1
        int tri = b / 3, rem = b - tri * 3;
        if (rem == 0) { which = 0; idx = tri; }
        else          { which = 1; idx = 2 * tri + rem - 1; }
    } else {                            // fallback: segmented
        which = (b < nb1) ? 0 : 1;
        idx = which ? (b - nb1) : b;
    }
    if (which == 0) gather_body<RELU1>(feat1, cur1, pad1, PAD1, out1, N1, idx);
    else            gather_body<RELU2>(feat2, cur2, pad2, PAD2, out2, N2, idx);
}

// out[n] = dot(x[n][:], hw) + hb
__global__ __launch_bounds__(256) void head_k(const float* __restrict__ x,
                                              const float* __restrict__ hw,
                                              const float* __restrict__ hb,
                                              float* __restrict__ out, int N) {
    int wid = threadIdx.x >> 6, lane = threadIdx.x & 63;
    int row = blockIdx.x * 4 + wid;
    if (row >= N) return;
    const float* xr = x + (size_t)row * DD;
    float v = xr[lane] * hw[lane] + xr[lane + 64] * hw[lane + 64];
    for (int off = 32; off > 0; off >>= 1) v += __shfl_down(v, off);
    if (lane == 0) out[row] = v + hb[0];
}

// ---------------- weight pre-split into PACKED fragment-order bf16 planes ----------------
// Packed p = ((kc*8 + t)*64 + lane)*8 + j  <->  W[t*16 + (lane&15)][kc*32 + (lane>>4)*8 + j]

struct W12 { const float* p[12]; };

__global__ __launch_bounds__(256) void wsplit_k(W12 ws, unsigned short* __restrict__ hi,
                                                unsigned short* __restrict__ lo) {
    int idx = blockIdx.x * 256 + threadIdx.x;
    if (idx >= 12 * DD * DD) return;
    int m = idx >> 14, pk = idx & 16383;
    int j = pk & 7, lane = (pk >> 3) & 63, t = (pk >> 9) & 7, kc = (pk >> 12) & 3;
    int src = (t * 16 + (lane & 15)) * DD + kc * 32 + (lane >> 4) * 8 + j;
    float x = ws.p[m][src];
    unsigned short h = rne_bf16(x);
    float r = x - __uint_as_float((unsigned int)h << 16);
    hi[idx] = h;
    lo[idx] = rne_bf16(r);
}

// ---------------- split-bf16 MFMA GEMM kernels (r10/r13 geometry, verified) ----------------
// FULL 3-product split: ah*bh + al*bh + ah*bl (~2^-18 residual).
// mfma_f32_16x16x32_bf16: A/B row = lane&15, k = (lane>>4)*8 + j; C/D col = lane&15,
// row = (lane>>4)*4 + reg.  4 waves, 16 rows/wave, 64-row blocks.

// fused steps 2+3: h = relu(X@W1^T+b1) block-local FP32 in LDS; Io -= (h@W2^T + b2)*(deg>0)
template <bool RELX>
__global__ __launch_bounds__(256) void fused23_k(
        const float* __restrict__ X,
        const unsigned short* __restrict__ W1h, const unsigned short* __restrict__ W1l,
        const float* __restrict__ B1,
        const unsigned short* __restrict__ W2h, const unsigned short* __restrict__ W2l,
        const float* __restrict__ B2,
        float* __restrict__ Io, int N, const int* __restrict__ deg) {
    __shared__ __align__(16) float hl[64][DD + 4];   // stride 132 f = 528B

    const int tid = threadIdx.x;
    const int w = tid >> 6, l = tid & 63;
    const int l15 = l & 15, lq = l >> 4;

    const int rowA = blockIdx.x * 64 + w * 16 + l15;
    const int rA = rowA < N ? rowA : N - 1;
    const float* xp = X + (size_t)rA * DD;

    bf16x8 ah[4], al[4];
#pragma unroll
    for (int kc = 0; kc < 4; ++kc)
        load_split8<RELX>(xp + kc * 32 + lq * 8, ah[kc], al[kc]);

    f32x4 acc[8];
#pragma unroll
    for (int t = 0; t < 8; ++t) acc[t] = (f32x4){0.f, 0.f, 0.f, 0.f};

#pragma unroll
    for (int kc = 0; kc < 4; ++kc) {
        const size_t fb = ((size_t)(kc * 8) * 64 + l) * 8;
        bf16x8 bh[8], bl[8];
#pragma unroll
        for (int t = 0; t < 8; ++t) bh[t] = *reinterpret_cast<const bf16x8*>(W1h + fb + t * 512);
#pragma unroll
        for (int t = 0; t < 8; ++t) bl[t] = *reinterpret_cast<const bf16x8*>(W1l + fb + t * 512);
#pragma unroll
        for (int t = 0; t < 8; ++t)
            acc[t] = __builtin_amdgcn_mfma_f32_16x16x32_bf16(ah[kc], bh[t], acc[t], 0, 0, 0);
#pragma unroll
        for (int t = 0; t < 8; ++t)
            acc[t] = __builtin_amdgcn_mfma_f32_16x16x32_bf16(al[kc], bh[t], acc[t], 0, 0, 0);
#pragma unroll
        for (int t = 0; t < 8; ++t)
            acc[t] = __builtin_amdgcn_mfma_f32_16x16x32_bf16(ah[kc], bl[t], acc[t], 0, 0, 0);
    }

    // h = relu(acc + b1) -> LDS fp32 (C/D layout rows w*16+lq*4+r)
    const int lr0 = w * 16 + lq * 4;
#pragma unroll
    for (int t = 0; t < 8; ++t) {
        const int col = t * 16 + l15;
        const float b = B1[col];
#pragma unroll
        for (int r = 0; r < 4; ++r)
            hl[lr0 + r][col] = fmaxf(acc[t][r] + b, 0.f);
    }
    __syncthreads();

    // read h back in A-frag layout + split (full fidelity)
    bf16x8 ah2[4], al2[4];
#pragma unroll
    for (int kc = 0; kc < 4; ++kc)
        load_split8<false>(&hl[w * 16 + l15][kc * 32 + lq * 8], ah2[kc], al2[kc]);

#pragma unroll
    for (int t = 0; t < 8; ++t) acc[t] = (f32x4){0.f, 0.f, 0.f, 0.f};

#pragma unroll
    for (int kc = 0; kc < 4; ++kc) {
        const size_t fb = ((size_t)(kc * 8) * 64 + l) * 8;
        bf16x8 bh[8], bl[8];
#pragma unroll
        for (int t = 0; t < 8; ++t) bh[t] = *reinterpret_cast<const bf16x8*>(W2h + fb + t * 512);
#pragma unroll
        for (int t = 0; t < 8; ++t) bl[t] = *reinterpret_cast<const bf16x8*>(W2l + fb + t * 512);
#pragma unroll
        for (int t = 0; t < 8; ++t)
            acc[t] = __builtin_amdgcn_mfma_f32_16x16x32_bf16(ah2[kc], bh[t], acc[t], 0, 0, 0);
#pragma unroll
        for (int t = 0; t < 8; ++t)
            acc[t] = __builtin_amdgcn_mfma_f32_16x16x32_bf16(al2[kc], bh[t], acc[t], 0, 0, 0);
#pragma unroll
        for (int t = 0; t < 8; ++t)
            acc[t] = __builtin_amdgcn_mfma_f32_16x16x32_bf16(ah2[kc], bl[t], acc[t], 0, 0, 0);
    }

    // epilogue: Io = Io - (acc + b2) * (deg>0)
    const int orow0 = blockIdx.x * 64 + w * 16 + lq * 4;
#pragma unroll
    for (int t = 0; t < 8; ++t) {
        const int col = t * 16 + l15;
        const float b2v = B2[col];
#pragma unroll
        for (int r = 0; r < 4; ++r) {
            const int grow = orow0 + r;
            if (grow >= N) continue;
            float fl = deg[grow] > 0 ? 1.f : 0.f;
            float* op = Io + (size_t)grow * DD + col;
            *op = *op - (acc[t][r] + b2v) * fl;
        }
    }
}

// dual GEMM (64-row blocks): out = relu( X1@W1^T + b1 + X2@W2^T + b2 );
// out may alias X1 (each wave reads only the rows it writes; reads precede stores).
template <bool RELX2>
__global__ __launch_bounds__(256) void gemm_dual_k(
        const float* __restrict__ X1,
        const unsigned short* __restrict__ W1h, const unsigned short* __restrict__ W1l,
        const float* __restrict__ B1,
        const float* __restrict__ X2,
        const unsigned short* __restrict__ W2h, const unsigned short* __restrict__ W2l,
        const float* __restrict__ B2,
        float* __restrict__ out, int N) {
    const int tid = threadIdx.x;
    const int w = tid >> 6, l = tid & 63;
    const int l15 = l & 15, lq = l >> 4;

    const int rowA = blockIdx.x * 64 + w * 16 + l15;
    const int rA = rowA < N ? rowA : N - 1;

    f32x4 acc[8];
#pragma unroll
    for (int t = 0; t < 8; ++t) acc[t] = (f32x4){0.f, 0.f, 0.f, 0.f};

    {
        bf16x8 ah[4], al[4];
#pragma unroll
        for (int kc = 0; kc < 4; ++kc)
            load_split8<false>(X1 + (size_t)rA * DD + kc * 32 + lq * 8, ah[kc], al[kc]);
#pragma unroll
        for (int kc = 0; kc < 4; ++kc) {
            const size_t fb = ((size_t)(kc * 8) * 64 + l) * 8;
            bf16x8 bh[8], bl[8];
#pragma unroll
            for (int t = 0; t < 8; ++t) bh[t] = *reinterpret_cast<const bf16x8*>(W1h + fb + t * 512);
#pragma unroll
            for (int t = 0; t < 8; ++t) bl[t] = *reinterpret_cast<const bf16x8*>(W1l + fb + t * 512);
#pragma unroll
            for (int t = 0; t < 8; ++t)
                acc[t] = __builtin_amdgcn_mfma_f32_16x16x32_bf16(ah[kc], bh[t], acc[t], 0, 0, 0);
#pragma unroll
            for (int t = 0; t < 8; ++t)
                acc[t] = __builtin_amdgcn_mfma_f32_16x16x32_bf16(al[kc], bh[t], acc[t], 0, 0, 0);
#pragma unroll
            for (int t = 0; t < 8; ++t)
                acc[t] = __builtin_amdgcn_mfma_f32_16x16x32_bf16(ah[kc], bl[t], acc[t], 0, 0, 0);
        }
    }
    {
        bf16x8 ah[4], al[4];
#pragma unroll
        for (int kc = 0; kc < 4; ++kc)
            load_split8<RELX2>(X2 + (size_t)rA * DD + kc * 32 + lq * 8, ah[kc], al[kc]);
#pragma unroll
        for (int kc = 0; kc < 4; ++kc) {
            const size_t fb = ((size_t)(kc * 8) * 64 + l) * 8;
            bf16x8 bh[8], bl[8];
#pragma unroll
            for (int t = 0; t < 8; ++t) bh[t] = *reinterpret_cast<const bf16x8*>(W2h + fb + t * 512);
#pragma unroll
            for (int t = 0; t < 8; ++t) bl[t] = *reinterpret_cast<const bf16x8*>(W2l + fb + t * 512);
#pragma unroll
            for (int t = 0; t < 8; ++t)
                acc[t] = __builtin_amdgcn_mfma_f32_16x16x32_bf16(ah[kc], bh[t], acc[t], 0, 0, 0);
#pragma unroll
            for (int t = 0; t < 8; ++t)
                acc[t] = __builtin_amdgcn_mfma_f32_16x16x32_bf16(al[kc], bh[t], acc[t], 0, 0, 0);
#pragma unroll
            for (int t = 0; t < 8; ++t)
                acc[t] = __builtin_amdgcn_mfma_f32_16x16x32_bf16(ah[kc], bl[t], acc[t], 0, 0, 0);
        }
    }

    const int orow0 = blockIdx.x * 64 + w * 16 + lq * 4;
#pragma unroll
    for (int t = 0; t < 8; ++t) {
        const int col = t * 16 + l15;
        const float bias = B1[col] + B2[col];
#pragma unroll
        for (int r = 0; r < 4; ++r) {
            const int grow = orow0 + r;
            if (grow >= N) continue;
            out[(size_t)grow * DD + col] = fmaxf(acc[t][r] + bias, 0.f);
        }
    }
}

// ---------------- host launch ----------------

extern "C" void kernel_launch(void* const* d_in, const int* in_sizes, int n_in,
                              void* d_out, int out_size, void* d_ws, size_t ws_size,
                              hipStream_t stream) {
    const float* emb_user = (const float*)d_in[0];
    const float* emb_item = (const float*)d_in[1];
    const float* head_W   = (const float*)d_in[26];
    const float* head_b   = (const float*)d_in[27];
    const int*   ue_src   = (const int*)d_in[28];
    const int*   ue_dst   = (const int*)d_in[29];
    const int*   iu_src   = (const int*)d_in[30];
    const int*   iu_dst   = (const int*)d_in[31];

    const int NU = in_sizes[0] / DD;
    const int NI = in_sizes[1] / DD;
    const int E  = in_sizes[28];

    const float* L[2][12];
    for (int l = 0; l < 2; ++l)
        for (int j = 0; j < 12; ++j) L[l][j] = (const float*)d_in[2 + l * 12 + j];

    // ---- workspace carve-up ----
    const size_t SU = (size_t)NU * DD, SI = (size_t)NI * DD;
    const size_t WPLANE = 12 * (size_t)DD * DD;
    size_t need = 0;
    auto pad256 = [](size_t b) { return (b + 255) & ~(size_t)255; };
    need += 2 * pad256(SU * 4) + pad256(SI * 4);
    need += pad256((size_t)NI * 4) + pad256((size_t)NU * 4);
    need += pad256((size_t)NI * PAD_I * 4) + pad256((size_t)NU * PAD_U * 4);
    need += 2 * pad256(WPLANE * 2);
    if (ws_size < need) return;  // fail via absmax instead of faulting

    char* w = (char*)d_ws;
    auto alloc = [&](size_t bytes) { void* p = w; w += pad256(bytes); return p; };
    float* Ua    = (float*)alloc(SU * 4);   // agg_u(L1) -> xu1
    float* Ub    = (float*)alloc(SU * 4);   // agg_u(L2) -> xu2
    float* Ia    = (float*)alloc(SI * 4);   // agg_i(L1) -> xi1
    int*   deg_i = (int*)alloc((size_t)NI * 4);
    int*   deg_u = (int*)alloc((size_t)NU * 4);
    int*   adj_i = (int*)alloc((size_t)NI * PAD_I * 4);
    int*   adj_u = (int*)alloc((size_t)NU * PAD_U * 4);
    unsigned short* Whi = (unsigned short*)alloc(WPLANE * 2);
    unsigned short* Wlo = (unsigned short*)alloc(WPLANE * 2);

    auto cdiv = [](long long a, long long b) { return (int)((a + b - 1) / b); };

    // pre-split + pack weights; plane order per layer l (base l*6): pW1, pW2, uiWn, uiWs, iuWn, iuWs
    W12 ws;
    for (int l = 0; l < 2; ++l) {
        ws.p[l * 6 + 0] = L[l][0];
        ws.p[l * 6 + 1] = L[l][2];
        ws.p[l * 6 + 2] = L[l][4];
        ws.p[l * 6 + 3] = L[l][6];
        ws.p[l * 6 + 4] = L[l][8];
        ws.p[l * 6 + 5] = L[l][10];
    }
    wsplit_k<<<cdiv(WPLANE, 256), 256, 0, stream>>>(ws, Whi, Wlo);

    // padded adjacency (layer-invariant)
    zeroi_k<<<cdiv(NI, 256), 256, 0, stream>>>(deg_i, NI);
    zeroi_k<<<cdiv(NU, 256), 256, 0, stream>>>(deg_u, NU);
    fill_k<<<cdiv(E, 256), 256, 0, stream>>>(ue_src, ue_dst, deg_i, adj_i, PAD_I, E);
    fill_k<<<cdiv(E, 256), 256, 0, stream>>>(iu_src, iu_dst, deg_u, adj_u, PAD_U, E);

    const int gI = cdiv(NI, 64), gU = cdiv(NU, 64);
    const int nbI = cdiv(NI, 4), nbU = cdiv(NU, 4);
    const size_t WM = (size_t)DD * DD;
    auto WH = [&](int l, int m) { return Whi + ((size_t)l * 6 + m) * WM; };
    auto WL = [&](int l, int m) { return Wlo + ((size_t)l * 6 + m) * WM; };

    // ---------------- layer 1 (relu applied at load from raw embeddings) ----------------
    // merged gathers: Ia = gmean(relu emb_user, adj_i);  Ua = gmean(relu emb_item, adj_u)
    gather2_k<true, true><<<nbI + nbU, 256, 0, stream>>>(
        emb_user, deg_i, adj_i, PAD_I, Ia, NI, nbI,
        emb_item, deg_u, adj_u, PAD_U, Ua, NU, nbU);
    // xu1 (Ua) = relu(Ua@iuWn + iubn + relu(emb_user)@iuWs + iubs)
    gemm_dual_k<true><<<gU, 256, 0, stream>>>(Ua, WH(0,4), WL(0,4), L[0][9],
                                              emb_user, WH(0,5), WL(0,5), L[0][11], Ua, NU);
    // Ia -= (relu(emb_item)@pW1 -> relu -> @pW2 + pb2) * (deg_i>0)
    fused23_k<true><<<gI, 256, 0, stream>>>(emb_item, WH(0,0), WL(0,0), L[0][1],
                                            WH(0,1), WL(0,1), L[0][3], Ia, NI, deg_i);
    // xi1 (Ia) = relu(Ia@uiWn + uibn + relu(emb_item)@uiWs + uibs)
    gemm_dual_k<true><<<gI, 256, 0, stream>>>(Ia, WH(0,2), WL(0,2), L[0][5],
                                              emb_item, WH(0,3), WL(0,3), L[0][7], Ia, NI);

    // ---------------- layer 2 (item branch is DEAD: head consumes only xu2) ----------------
    // Ub = gmean(xi1, adj_u)
    gather_mean_k<false><<<nbU, 256, 0, stream>>>(Ia, deg_u, adj_u, PAD_U, Ub, NU);
    // xu2 (Ub) = relu(Ub@iuWn(L2) + iubn + xu1@iuWs(L2) + iubs)
    gemm_dual_k<false><<<gU, 256, 0, stream>>>(Ub, WH(1,4), WL(1,4), L[1][9],
                                               Ua, WH(1,5), WL(1,5), L[1][11], Ub, NU);

    head_k<<<cdiv(NU, 4), 256, 0, stream>>>(Ub, head_W, head_b, (float*)d_out, NU);
}

// Round 15
// 453.808 us; speedup vs baseline: 1.6370x; 1.0111x over previous
//
#include <hip/hip_runtime.h>
#include <hip/hip_bf16.h>

#define DD 128      // feature dim
#define PAD_I 64    // max item in-degree (Poisson(16); P(overflow) ~ 1e-6, guarded)
#define PAD_U 48    // max user in-degree (Poisson(8);  P(overflow) ~ 1e-9, guarded)

typedef __attribute__((ext_vector_type(8))) short bf16x8;
typedef __attribute__((ext_vector_type(4))) float f32x4;

// manual RNE fp32 -> bf16 (one-time weight prep only)
__device__ __forceinline__ unsigned short rne_bf16(float x) {
    unsigned int u = __float_as_uint(x);
    return (unsigned short)((u + 0x7FFFu + ((u >> 16) & 1u)) >> 16);
}

// load 8 contiguous fp32 (optionally relu) -> hi+lo bf16 frags (v_cvt_pk_bf16_f32 path)
template <bool R>
__device__ __forceinline__ void load_split8(const float* __restrict__ p,
                                            bf16x8& hf, bf16x8& lf) {
    float4 v0 = *reinterpret_cast<const float4*>(p);
    float4 v1 = *reinterpret_cast<const float4*>(p + 4);
    float x[8] = {v0.x, v0.y, v0.z, v0.w, v1.x, v1.y, v1.z, v1.w};
#pragma unroll
    for (int j = 0; j < 8; j += 2) {
        float a = R ? fmaxf(x[j], 0.f) : x[j];
        float b = R ? fmaxf(x[j + 1], 0.f) : x[j + 1];
        __hip_bfloat162 h2 = __float22bfloat162_rn(make_float2(a, b));
        float2 hr = __bfloat1622float2(h2);
        __hip_bfloat162 l2 = __float22bfloat162_rn(make_float2(a - hr.x, b - hr.y));
        hf[j]     = (short)__bfloat16_as_ushort(h2.x);
        hf[j + 1] = (short)__bfloat16_as_ushort(h2.y);
        lf[j]     = (short)__bfloat16_as_ushort(l2.x);
        lf[j + 1] = (short)__bfloat16_as_ushort(l2.y);
    }
}

// ---------------- misc kernels ----------------

__global__ __launch_bounds__(256) void zeroi_k(int* __restrict__ p, int n) {
    int gid = blockIdx.x * 256 + threadIdx.x;
    if (gid < n) p[gid] = 0;
}

__global__ __launch_bounds__(256) void fill_k(const int* __restrict__ src,
                                              const int* __restrict__ dst,
                                              int* __restrict__ cur,
                                              int* __restrict__ pad, int PAD, int E) {
    int e = blockIdx.x * 256 + threadIdx.x;
    if (e >= E) return;
    int d = dst[e];
    int slot = atomicAdd(&cur[d], 1);
    if (slot < PAD) pad[(size_t)d * PAD + slot] = src[e];
}

// gather body v2: 4 rows/block, 1 wave/row. 4 x 16-lane groups: group p = lane>>4
// owns edges e == p (mod 4); lane covers cols c*8..c*8+7 (2 float4). DIRECT pl[j]
// index loads (NO shfl — divergent-exec shfl is undefined, r9 lesson). 2-edge
// unroll -> 4 float4 in flight per lane, 16 per wave. Reduce xor16+xor32.
template <bool RELU>
__device__ __forceinline__ void gather_body(const float* __restrict__ feat,
                                            const int* __restrict__ cur,
                                            const int* __restrict__ pad, int PAD,
                                            float* __restrict__ out, int N, int blk) {
    int row = blk * 4 + (threadIdx.x >> 6);
    if (row >= N) return;
    int lane = threadIdx.x & 63;
    int p = lane >> 4, c = lane & 15;
    int deg = cur[row]; if (deg > PAD) deg = PAD;
    const int* pl = pad + (size_t)row * PAD;

    float4 a0 = make_float4(0.f, 0.f, 0.f, 0.f);
    float4 a1 = make_float4(0.f, 0.f, 0.f, 0.f);
    float4 b0 = make_float4(0.f, 0.f, 0.f, 0.f);
    float4 b1 = make_float4(0.f, 0.f, 0.f, 0.f);
    int j = p;
    for (; j + 4 < deg; j += 8) {
        int s0 = pl[j];
        int s1 = pl[j + 4];
        const float* q0 = feat + (size_t)s0 * DD + c * 8;
        const float* q1 = feat + (size_t)s1 * DD + c * 8;
        float4 u0 = *reinterpret_cast<const float4*>(q0);
        float4 u1 = *reinterpret_cast<const float4*>(q0 + 4);
        float4 u2 = *reinterpret_cast<const float4*>(q1);
        float4 u3 = *reinterpret_cast<const float4*>(q1 + 4);
        if (RELU) {
            u0.x = fmaxf(u0.x, 0.f); u0.y = fmaxf(u0.y, 0.f); u0.z = fmaxf(u0.z, 0.f); u0.w = fmaxf(u0.w, 0.f);
            u1.x = fmaxf(u1.x, 0.f); u1.y = fmaxf(u1.y, 0.f); u1.z = fmaxf(u1.z, 0.f); u1.w = fmaxf(u1.w, 0.f);
            u2.x = fmaxf(u2.x, 0.f); u2.y = fmaxf(u2.y, 0.f); u2.z = fmaxf(u2.z, 0.f); u2.w = fmaxf(u2.w, 0.f);
            u3.x = fmaxf(u3.x, 0.f); u3.y = fmaxf(u3.y, 0.f); u3.z = fmaxf(u3.z, 0.f); u3.w = fmaxf(u3.w, 0.f);
        }
        a0.x += u0.x; a0.y += u0.y; a0.z += u0.z; a0.w += u0.w;
        a1.x += u1.x; a1.y += u1.y; a1.z += u1.z; a1.w += u1.w;
        b0.x += u2.x; b0.y += u2.y; b0.z += u2.z; b0.w += u2.w;
        b1.x += u3.x; b1.y += u3.y; b1.z += u3.z; b1.w += u3.w;
    }
    if (j < deg) {
        int s = pl[j];
        const float* q = feat + (size_t)s * DD + c * 8;
        float4 u0 = *reinterpret_cast<const float4*>(q);
        float4 u1 = *reinterpret_cast<const float4*>(q + 4);
        if (RELU) {
            u0.x = fmaxf(u0.x, 0.f); u0.y = fmaxf(u0.y, 0.f); u0.z = fmaxf(u0.z, 0.f); u0.w = fmaxf(u0.w, 0.f);
            u1.x = fmaxf(u1.x, 0.f); u1.y = fmaxf(u1.y, 0.f); u1.z = fmaxf(u1.z, 0.f); u1.w = fmaxf(u1.w, 0.f);
        }
        a0.x += u0.x; a0.y += u0.y; a0.z += u0.z; a0.w += u0.w;
        a1.x += u1.x; a1.y += u1.y; a1.z += u1.z; a1.w += u1.w;
    }
    a0.x += b0.x; a0.y += b0.y; a0.z += b0.z; a0.w += b0.w;
    a1.x += b1.x; a1.y += b1.y; a1.z += b1.z; a1.w += b1.w;

#pragma unroll
    for (int off = 16; off <= 32; off <<= 1) {
        a0.x += __shfl_xor(a0.x, off); a0.y += __shfl_xor(a0.y, off);
        a0.z += __shfl_xor(a0.z, off); a0.w += __shfl_xor(a0.w, off);
        a1.x += __shfl_xor(a1.x, off); a1.y += __shfl_xor(a1.y, off);
        a1.z += __shfl_xor(a1.z, off); a1.w += __shfl_xor(a1.w, off);
    }
    if (p == 0) {
        float iv = 1.0f / (float)(deg > 1 ? deg : 1);
        a0.x *= iv; a0.y *= iv; a0.z *= iv; a0.w *= iv;
        a1.x *= iv; a1.y *= iv; a1.z *= iv; a1.w *= iv;
        float* o = out + (size_t)row * DD + c * 8;
        *reinterpret_cast<float4*>(o) = a0;
        *reinterpret_cast<float4*>(o + 4) = a1;
    }
}

// standalone gather (L2 user gather)
template <bool RELU>
__global__ __launch_bounds__(256) void gather_mean_k(const float* __restrict__ feat,
                                                     const int* __restrict__ cur,
                                                     const int* __restrict__ pad, int PAD,
                                                     float* __restrict__ out, int N) {
    gather_body<RELU>(feat, cur, pad, PAD, out, N, blockIdx.x);
}

// merged dual gather (L1): task1 (nb1 blocks) + task2 (nb2 blocks), 1:2 block stripe
template <bool RELU1, bool RELU2>
__global__ __launch_bounds__(256) void gather2_k(
        const float* __restrict__ feat1, const int* __restrict__ cur1,
        const int* __restrict__ pad1, int PAD1, float* __restrict__ out1, int N1, int nb1,
        const float* __restrict__ feat2, const int* __restrict__ cur2,
        const int* __restrict__ pad2, int PAD2, float* __restrict__ out2, int N2, int nb2) {
    int b = blockIdx.x;
    int which, idx;
    if (nb2 == 2 * nb1) {
        int tri = b / 3, rem = b - tri * 3;
        if (rem == 0) { which = 0; idx = tri; }
        else          { which = 1; idx = 2 * tri + rem - 1; }
    } else {
        which = (b < nb1) ? 0 : 1;
        idx = which ? (b - nb1) : b;
    }
    if (which == 0) gather_body<RELU1>(feat1, cur1, pad1, PAD1, out1, N1, idx);
    else            gather_body<RELU2>(feat2, cur2, pad2, PAD2, out2, N2, idx);
}

// out[n] = dot(x[n][:], hw) + hb
__global__ __launch_bounds__(256) void head_k(const float* __restrict__ x,
                                              const float* __restrict__ hw,
                                              const float* __restrict__ hb,
                                              float* __restrict__ out, int N) {
    int wid = threadIdx.x >> 6, lane = threadIdx.x & 63;
    int row = blockIdx.x * 4 + wid;
    if (row >= N) return;
    const float* xr = x + (size_t)row * DD;
    float v = xr[lane] * hw[lane] + xr[lane + 64] * hw[lane + 64];
    for (int off = 32; off > 0; off >>= 1) v += __shfl_down(v, off);
    if (lane == 0) out[row] = v + hb[0];
}

// ---------------- weight pre-split into PACKED fragment-order bf16 planes ----------------
// Packed p = ((kc*8 + t)*64 + lane)*8 + j  <->  W[t*16 + (lane&15)][kc*32 + (lane>>4)*8 + j]

struct W12 { const float* p[12]; };

__global__ __launch_bounds__(256) void wsplit_k(W12 ws, unsigned short* __restrict__ hi,
                                                unsigned short* __restrict__ lo) {
    int idx = blockIdx.x * 256 + threadIdx.x;
    if (idx >= 12 * DD * DD) return;
    int m = idx >> 14, pk = idx & 16383;
    int j = pk & 7, lane = (pk >> 3) & 63, t = (pk >> 9) & 7, kc = (pk >> 12) & 3;
    int src = (t * 16 + (lane & 15)) * DD + kc * 32 + (lane >> 4) * 8 + j;
    float x = ws.p[m][src];
    unsigned short h = rne_bf16(x);
    float r = x - __uint_as_float((unsigned int)h << 16);
    hi[idx] = h;
    lo[idx] = rne_bf16(r);
}

// ---------------- split-bf16 MFMA GEMM kernels (r10/r13 geometry, verified) ----------------
// FULL 3-product split: ah*bh + al*bh + ah*bl (~2^-18 residual).
// mfma_f32_16x16x32_bf16: A/B row = lane&15, k = (lane>>4)*8 + j; C/D col = lane&15,
// row = (lane>>4)*4 + reg.  4 waves, 16 rows/wave, 64-row blocks.

// fused steps 2+3: h = relu(X@W1^T+b1) block-local FP32 in LDS; Io -= (h@W2^T + b2)*(deg>0)
template <bool RELX>
__global__ __launch_bounds__(256) void fused23_k(
        const float* __restrict__ X,
        const unsigned short* __restrict__ W1h, const unsigned short* __restrict__ W1l,
        const float* __restrict__ B1,
        const unsigned short* __restrict__ W2h, const unsigned short* __restrict__ W2l,
        const float* __restrict__ B2,
        float* __restrict__ Io, int N, const int* __restrict__ deg) {
    __shared__ __align__(16) float hl[64][DD + 4];   // stride 132 f = 528B

    const int tid = threadIdx.x;
    const int w = tid >> 6, l = tid & 63;
    const int l15 = l & 15, lq = l >> 4;

    const int rowA = blockIdx.x * 64 + w * 16 + l15;
    const int rA = rowA < N ? rowA : N - 1;
    const float* xp = X + (size_t)rA * DD;

    bf16x8 ah[4], al[4];
#pragma unroll
    for (int kc = 0; kc < 4; ++kc)
        load_split8<RELX>(xp + kc * 32 + lq * 8, ah[kc], al[kc]);

    f32x4 acc[8];
#pragma unroll
    for (int t = 0; t < 8; ++t) acc[t] = (f32x4){0.f, 0.f, 0.f, 0.f};

#pragma unroll
    for (int kc = 0; kc < 4; ++kc) {
        const size_t fb = ((size_t)(kc * 8) * 64 + l) * 8;
        bf16x8 bh[8], bl[8];
#pragma unroll
        for (int t = 0; t < 8; ++t) bh[t] = *reinterpret_cast<const bf16x8*>(W1h + fb + t * 512);
#pragma unroll
        for (int t = 0; t < 8; ++t) bl[t] = *reinterpret_cast<const bf16x8*>(W1l + fb + t * 512);
#pragma unroll
        for (int t = 0; t < 8; ++t)
            acc[t] = __builtin_amdgcn_mfma_f32_16x16x32_bf16(ah[kc], bh[t], acc[t], 0, 0, 0);
#pragma unroll
        for (int t = 0; t < 8; ++t)
            acc[t] = __builtin_amdgcn_mfma_f32_16x16x32_bf16(al[kc], bh[t], acc[t], 0, 0, 0);
#pragma unroll
        for (int t = 0; t < 8; ++t)
            acc[t] = __builtin_amdgcn_mfma_f32_16x16x32_bf16(ah[kc], bl[t], acc[t], 0, 0, 0);
    }

    // h = relu(acc + b1) -> LDS fp32 (C/D layout rows w*16+lq*4+r)
    const int lr0 = w * 16 + lq * 4;
#pragma unroll
    for (int t = 0; t < 8; ++t) {
        const int col = t * 16 + l15;
        const float b = B1[col];
#pragma unroll
        for (int r = 0; r < 4; ++r)
            hl[lr0 + r][col] = fmaxf(acc[t][r] + b, 0.f);
    }
    __syncthreads();

    // read h back in A-frag layout + split (full fidelity)
    bf16x8 ah2[4], al2[4];
#pragma unroll
    for (int kc = 0; kc < 4; ++kc)
        load_split8<false>(&hl[w * 16 + l15][kc * 32 + lq * 8], ah2[kc], al2[kc]);

#pragma unroll
    for (int t = 0; t < 8; ++t) acc[t] = (f32x4){0.f, 0.f, 0.f, 0.f};

#pragma unroll
    for (int kc = 0; kc < 4; ++kc) {
        const size_t fb = ((size_t)(kc * 8) * 64 + l) * 8;
        bf16x8 bh[8], bl[8];
#pragma unroll
        for (int t = 0; t < 8; ++t) bh[t] = *reinterpret_cast<const bf16x8*>(W2h + fb + t * 512);
#pragma unroll
        for (int t = 0; t < 8; ++t) bl[t] = *reinterpret_cast<const bf16x8*>(W2l + fb + t * 512);
#pragma unroll
        for (int t = 0; t < 8; ++t)
            acc[t] = __builtin_amdgcn_mfma_f32_16x16x32_bf16(ah2[kc], bh[t], acc[t], 0, 0, 0);
#pragma unroll
        for (int t = 0; t < 8; ++t)
            acc[t] = __builtin_amdgcn_mfma_f32_16x16x32_bf16(al2[kc], bh[t], acc[t], 0, 0, 0);
#pragma unroll
        for (int t = 0; t < 8; ++t)
            acc[t] = __builtin_amdgcn_mfma_f32_16x16x32_bf16(ah2[kc], bl[t], acc[t], 0, 0, 0);
    }

    // epilogue: Io = Io - (acc + b2) * (deg>0)
    const int orow0 = blockIdx.x * 64 + w * 16 + lq * 4;
#pragma unroll
    for (int t = 0; t < 8; ++t) {
        const int col = t * 16 + l15;
        const float b2v = B2[col];
#pragma unroll
        for (int r = 0; r < 4; ++r) {
            const int grow = orow0 + r;
            if (grow >= N) continue;
            float fl = deg[grow] > 0 ? 1.f : 0.f;
            float* op = Io + (size_t)grow * DD + col;
            *op = *op - (acc[t][r] + b2v) * fl;
        }
    }
}

// dual GEMM (64-row blocks): out = relu( X1@W1^T + b1 + X2@W2^T + b2 );
// out may alias X1 (each wave reads only the rows it writes; reads precede stores).
template <bool RELX2>
__global__ __launch_bounds__(256) void gemm_dual_k(
        const float* __restrict__ X1,
        const unsigned short* __restrict__ W1h, const unsigned short* __restrict__ W1l,
        const float* __restrict__ B1,
        const float* __restrict__ X2,
        const unsigned short* __restrict__ W2h, const unsigned short* __restrict__ W2l,
        const float* __restrict__ B2,
        float* __restrict__ out, int N) {
    const int tid = threadIdx.x;
    const int w = tid >> 6, l = tid & 63;
    const int l15 = l & 15, lq = l >> 4;

    const int rowA = blockIdx.x * 64 + w * 16 + l15;
    const int rA = rowA < N ? rowA : N - 1;

    f32x4 acc[8];
#pragma unroll
    for (int t = 0; t < 8; ++t) acc[t] = (f32x4){0.f, 0.f, 0.f, 0.f};

    {
        bf16x8 ah[4], al[4];
#pragma unroll
        for (int kc = 0; kc < 4; ++kc)
            load_split8<false>(X1 + (size_t)rA * DD + kc * 32 + lq * 8, ah[kc], al[kc]);
#pragma unroll
        for (int kc = 0; kc < 4; ++kc) {
            const size_t fb = ((size_t)(kc * 8) * 64 + l) * 8;
            bf16x8 bh[8], bl[8];
#pragma unroll
            for (int t = 0; t < 8; ++t) bh[t] = *reinterpret_cast<const bf16x8*>(W1h + fb + t * 512);
#pragma unroll
            for (int t = 0; t < 8; ++t) bl[t] = *reinterpret_cast<const bf16x8*>(W1l + fb + t * 512);
#pragma unroll
            for (int t = 0; t < 8; ++t)
                acc[t] = __builtin_amdgcn_mfma_f32_16x16x32_bf16(ah[kc], bh[t], acc[t], 0, 0, 0);
#pragma unroll
            for (int t = 0; t < 8; ++t)
                acc[t] = __builtin_amdgcn_mfma_f32_16x16x32_bf16(al[kc], bh[t], acc[t], 0, 0, 0);
#pragma unroll
            for (int t = 0; t < 8; ++t)
                acc[t] = __builtin_amdgcn_mfma_f32_16x16x32_bf16(ah[kc], bl[t], acc[t], 0, 0, 0);
        }
    }
    {
        bf16x8 ah[4], al[4];
#pragma unroll
        for (int kc = 0; kc < 4; ++kc)
            load_split8<RELX2>(X2 + (size_t)rA * DD + kc * 32 + lq * 8, ah[kc], al[kc]);
#pragma unroll
        for (int kc = 0; kc < 4; ++kc) {
            const size_t fb = ((size_t)(kc * 8) * 64 + l) * 8;
            bf16x8 bh[8], bl[8];
#pragma unroll
            for (int t = 0; t < 8; ++t) bh[t] = *reinterpret_cast<const bf16x8*>(W2h + fb + t * 512);
#pragma unroll
            for (int t = 0; t < 8; ++t) bl[t] = *reinterpret_cast<const bf16x8*>(W2l + fb + t * 512);
#pragma unroll
            for (int t = 0; t < 8; ++t)
                acc[t] = __builtin_amdgcn_mfma_f32_16x16x32_bf16(ah[kc], bh[t], acc[t], 0, 0, 0);
#pragma unroll
            for (int t = 0; t < 8; ++t)
                acc[t] = __builtin_amdgcn_mfma_f32_16x16x32_bf16(al[kc], bh[t], acc[t], 0, 0, 0);
#pragma unroll
            for (int t = 0; t < 8; ++t)
                acc[t] = __builtin_amdgcn_mfma_f32_16x16x32_bf16(ah[kc], bl[t], acc[t], 0, 0, 0);
        }
    }

    const int orow0 = blockIdx.x * 64 + w * 16 + lq * 4;
#pragma unroll
    for (int t = 0; t < 8; ++t) {
        const int col = t * 16 + l15;
        const float bias = B1[col] + B2[col];
#pragma unroll
        for (int r = 0; r < 4; ++r) {
            const int grow = orow0 + r;
            if (grow >= N) continue;
            out[(size_t)grow * DD + col] = fmaxf(acc[t][r] + bias, 0.f);
        }
    }
}

// ---------------- host launch ----------------

extern "C" void kernel_launch(void* const* d_in, const int* in_sizes, int n_in,
                              void* d_out, int out_size, void* d_ws, size_t ws_size,
                              hipStream_t stream) {
    const float* emb_user = (const float*)d_in[0];
    const float* emb_item = (const float*)d_in[1];
    const float* head_W   = (const float*)d_in[26];
    const float* head_b   = (const float*)d_in[27];
    const int*   ue_src   = (const int*)d_in[28];
    const int*   ue_dst   = (const int*)d_in[29];
    const int*   iu_src   = (const int*)d_in[30];
    const int*   iu_dst   = (const int*)d_in[31];

    const int NU = in_sizes[0] / DD;
    const int NI = in_sizes[1] / DD;
    const int E  = in_sizes[28];

    const float* L[2][12];
    for (int l = 0; l < 2; ++l)
        for (int j = 0; j < 12; ++j) L[l][j] = (const float*)d_in[2 + l * 12 + j];

    // ---- workspace carve-up ----
    const size_t SU = (size_t)NU * DD, SI = (size_t)NI * DD;
    const size_t WPLANE = 12 * (size_t)DD * DD;
    size_t need = 0;
    auto pad256 = [](size_t b) { return (b + 255) & ~(size_t)255; };
    need += 2 * pad256(SU * 4) + pad256(SI * 4);
    need += pad256((size_t)NI * 4) + pad256((size_t)NU * 4);
    need += pad256((size_t)NI * PAD_I * 4) + pad256((size_t)NU * PAD_U * 4);
    need += 2 * pad256(WPLANE * 2);
    if (ws_size < need) return;  // fail via absmax instead of faulting

    char* w = (char*)d_ws;
    auto alloc = [&](size_t bytes) { void* p = w; w += pad256(bytes); return p; };
    float* Ua    = (float*)alloc(SU * 4);   // agg_u(L1) -> xu1
    float* Ub    = (float*)alloc(SU * 4);   // agg_u(L2) -> xu2
    float* Ia    = (float*)alloc(SI * 4);   // agg_i(L1) -> xi1
    int*   deg_i = (int*)alloc((size_t)NI * 4);
    int*   deg_u = (int*)alloc((size_t)NU * 4);
    int*   adj_i = (int*)alloc((size_t)NI * PAD_I * 4);
    int*   adj_u = (int*)alloc((size_t)NU * PAD_U * 4);
    unsigned short* Whi = (unsigned short*)alloc(WPLANE * 2);
    unsigned short* Wlo = (unsigned short*)alloc(WPLANE * 2);

    auto cdiv = [](long long a, long long b) { return (int)((a + b - 1) / b); };

    // pre-split + pack weights; plane order per layer l (base l*6): pW1, pW2, uiWn, uiWs, iuWn, iuWs
    W12 ws;
    for (int l = 0; l < 2; ++l) {
        ws.p[l * 6 + 0] = L[l][0];
        ws.p[l * 6 + 1] = L[l][2];
        ws.p[l * 6 + 2] = L[l][4];
        ws.p[l * 6 + 3] = L[l][6];
        ws.p[l * 6 + 4] = L[l][8];
        ws.p[l * 6 + 5] = L[l][10];
    }
    wsplit_k<<<cdiv(WPLANE, 256), 256, 0, stream>>>(ws, Whi, Wlo);

    // padded adjacency (layer-invariant)
    zeroi_k<<<cdiv(NI, 256), 256, 0, stream>>>(deg_i, NI);
    zeroi_k<<<cdiv(NU, 256), 256, 0, stream>>>(deg_u, NU);
    fill_k<<<cdiv(E, 256), 256, 0, stream>>>(ue_src, ue_dst, deg_i, adj_i, PAD_I, E);
    fill_k<<<cdiv(E, 256), 256, 0, stream>>>(iu_src, iu_dst, deg_u, adj_u, PAD_U, E);

    const int gI = cdiv(NI, 64), gU = cdiv(NU, 64);
    const int nbI = cdiv(NI, 4), nbU = cdiv(NU, 4);
    const size_t WM = (size_t)DD * DD;
    auto WH = [&](int l, int m) { return Whi + ((size_t)l * 6 + m) * WM; };
    auto WL = [&](int l, int m) { return Wlo + ((size_t)l * 6 + m) * WM; };

    // ---------------- layer 1 (relu applied at load from raw embeddings) ----------------
    // merged gathers: Ia = gmean(relu emb_user, adj_i);  Ua = gmean(relu emb_item, adj_u)
    gather2_k<true, true><<<nbI + nbU, 256, 0, stream>>>(
        emb_user, deg_i, adj_i, PAD_I, Ia, NI, nbI,
        emb_item, deg_u, adj_u, PAD_U, Ua, NU, nbU);
    // xu1 (Ua) = relu(Ua@iuWn + iubn + relu(emb_user)@iuWs + iubs)
    gemm_dual_k<true><<<gU, 256, 0, stream>>>(Ua, WH(0,4), WL(0,4), L[0][9],
                                              emb_user, WH(0,5), WL(0,5), L[0][11], Ua, NU);
    // Ia -= (relu(emb_item)@pW1 -> relu -> @pW2 + pb2) * (deg_i>0)
    fused23_k<true><<<gI, 256, 0, stream>>>(emb_item, WH(0,0), WL(0,0), L[0][1],
                                            WH(0,1), WL(0,1), L[0][3], Ia, NI, deg_i);
    // xi1 (Ia) = relu(Ia@uiWn + uibn + relu(emb_item)@uiWs + uibs)
    gemm_dual_k<true><<<gI, 256, 0, stream>>>(Ia, WH(0,2), WL(0,2), L[0][5],
                                              emb_item, WH(0,3), WL(0,3), L[0][7], Ia, NI);

    // ---------------- layer 2 (item branch is DEAD: head consumes only xu2) ----------------
    // Ub = gmean(xi1, adj_u)
    gather_mean_k<false><<<nbU, 256, 0, stream>>>(Ia, deg_u, adj_u, PAD_U, Ub, NU);
    // xu2 (Ub) = relu(Ub@iuWn(L2) + iubn + xu1@iuWs(L2) + iubs)
    gemm_dual_k<false><<<gU, 256, 0, stream>>>(Ub, WH(1,4), WL(1,4), L[1][9],
                                               Ua, WH(1,5), WL(1,5), L[1][11], Ub, NU);

    head_k<<<cdiv(NU, 4), 256, 0, stream>>>(Ub, head_W, head_b, (float*)d_out, NU);
}